// Round 3
// baseline (205.126 us; speedup 1.0000x reference)
//
#include <hip/hip_runtime.h>

#define NN 2000

typedef _Float16 halfx8 __attribute__((ext_vector_type(8)));
typedef float floatx4 __attribute__((ext_vector_type(4)));

// lgkm-only barrier: LDS visibility without draining vmcnt (global loads stay
// in flight across phase boundaries). "memory" clobber pins compiler ordering.
#define LBAR() asm volatile("s_waitcnt lgkmcnt(0)\n\ts_barrier" ::: "memory")

// f32 -> OCP fp8 e4m3 (gfx950 HW convert; same format the fp8 MFMA consumes)
__device__ __forceinline__ unsigned char to_fp8(float v) {
    return (unsigned char)(__builtin_amdgcn_cvt_pk_fp8_f32(v, 0.f, 0, false) & 0xff);
}

// ---------------------------------------------------------------------------
// Kernel 1: sorted neighbor lists. float4 adj loads (4x fewer VMEM issues than
// scalar), 4-ballot prefix scan per 256-col chunk. Also zero-inits the fused
// finalize accumulator + both counters (stream-ordered ahead of use).
// ---------------------------------------------------------------------------
__global__ void build_nbrs_k(const float* __restrict__ adj,
                             int* __restrict__ nbrs,
                             float* __restrict__ gsum) {
    int i = blockIdx.x;
    int lane = threadIdx.x;
    if (i == 0 && lane == 0) {
        gsum[0] = 0.0f;                      // fused-finalize accumulator
        ((unsigned*)gsum)[1] = 0u;           // finalize contribution counter
        ((unsigned*)gsum)[2] = 0u;           // step<0> completion/ticket counter
    }
    const float4* row = (const float4*)(adj + (size_t)i * NN);  // 500 float4s
    float4 v[8];
#pragma unroll
    for (int c = 0; c < 8; ++c) {
        int idx4 = c * 64 + lane;
        if (idx4 < 500) v[c] = row[idx4];
        else            v[c] = make_float4(0.f, 0.f, 0.f, 0.f);
    }
    int base = 0;
#pragma unroll
    for (int c = 0; c < 8; ++c) {
        unsigned nib = (v[c].x > 0.5f ? 1u : 0u) | (v[c].y > 0.5f ? 2u : 0u) |
                       (v[c].z > 0.5f ? 4u : 0u) | (v[c].w > 0.5f ? 8u : 0u);
        unsigned long long b0 = __ballot(nib & 1u);
        unsigned long long b1 = __ballot(nib & 2u);
        unsigned long long b2 = __ballot(nib & 4u);
        unsigned long long b3 = __ballot(nib & 8u);
        unsigned long long below = (1ull << lane) - 1ull;
        int pos = base + __popcll(b0 & below) + __popcll(b1 & below) +
                         __popcll(b2 & below) + __popcll(b3 & below);
        int col0 = c * 256 + lane * 4;
        if (nib & 1u) { nbrs[i * 16 + pos] = col0;     ++pos; }
        if (nib & 2u) { nbrs[i * 16 + pos] = col0 + 1; ++pos; }
        if (nib & 4u) { nbrs[i * 16 + pos] = col0 + 2; ++pos; }
        if (nib & 8u) { nbrs[i * 16 + pos] = col0 + 3; ++pos; }
        base += __popcll(b0) + __popcll(b1) + __popcll(b2) + __popcll(b3);
    }
}

// ---------------------------------------------------------------------------
// Kernel 2 (fused): per-(i,m) maps + aux descriptor (blocks 0..124) and
// W1/W2 MFMA B-fragment packing (blocks 125..164).
//   map8[i][m][a] = p : nbrs[j][p]==nbrs[i][a] (or -1), j=nbrs[i][m]
//   imp8[i][m][p] = a (inverse, or -1)
//   aux = { j,  a1|pa1<<8|a2<<16|pa2<<24,  vm|pmm<<16|ms<<24, 0 }
// PRE chunks (maps, fp8 e4m3): c0=(blk2|blk4) c1=(blk6|blk8) c2=(blk10|-)
//   for ACC1; c3=(3|5) c4=(7|9) c5=(11|-) for ACC2.  (k<16 -> first blk)
// POST chunks (S0/V, f16): d0=(blk0|blk12) d1=(blk14|blk16) ACC1;
//   d2=(1|13) d3=(15|17) ACC2.
// B-frag: lane L holds B[k=(L>>4)*8+j][n=L&15].
// ---------------------------------------------------------------------------
__global__ void build_map_prep_k(const int* __restrict__ nbrs,
                                 signed char* __restrict__ map8,
                                 signed char* __restrict__ imp8,
                                 int4* __restrict__ aux,
                                 const float* __restrict__ W1,
                                 const float* __restrict__ W2,
                                 unsigned char* __restrict__ Wpk8,
                                 _Float16* __restrict__ Wpk16) {
    if (blockIdx.x >= 125) {
        // ---- weight-packing part ----
        int idx = (blockIdx.x - 125) * 256 + threadIdx.x;
        if (idx >= 10240) return;
        if (idx < 6144) {            // fp8 PRE: [2][6][64][8] bytes
            int stage = idx / 3072;
            int r = idx % 3072;
            int c = r / 512;
            int r2 = r % 512;
            int L = r2 >> 3, jj = r2 & 7;
            int q = L >> 4, h = L & 15;
            int k = q * 8 + jj;
            const int bA[6] = {2, 6, 10, 3, 7, 11};
            const int bB[6] = {4, 8, -1, 5, 9, -1};
            int tb = (k < 16) ? bA[c] : bB[c];
            int ci = k & 15;
            const float* W = stage ? W2 : W1;
            float val = (tb < 0) ? 0.f : W[h * 288 + tb * 16 + ci];
            Wpk8[idx] = to_fp8(val);
        } else {                     // f16 POST: [2][4][64][8] halves
            int id2 = idx - 6144;
            int stage = id2 / 2048;
            int r = id2 % 2048;
            int c = r / 512;
            int r2 = r % 512;
            int L = r2 >> 3, jj = r2 & 7;
            int q = L >> 4, h = L & 15;
            int k = q * 8 + jj;
            const int bA[4] = {0, 14, 1, 15};
            const int bB[4] = {12, 16, 13, 17};
            int tb = (k < 16) ? bA[c] : bB[c];
            int ci = k & 15;
            const float* W = stage ? W2 : W1;
            float val = W[h * 288 + tb * 16 + ci];
            Wpk16[id2] = (_Float16)val;
        }
        return;
    }
    // ---- map-building part ----
    int idx = blockIdx.x * 256 + threadIdx.x;  // (i,m)
    if (idx >= NN * 16) return;
    int i = idx >> 4;
    int m = idx & 15;
    int j = nbrs[idx];
    const int4* pi = (const int4*)(nbrs + (size_t)i * 16);
    const int4* pj = (const int4*)(nbrs + (size_t)j * 16);
    int4 A = pi[0], Bq = pi[1], C = pi[2], D = pi[3];
    int4 E = pj[0], F = pj[1], G = pj[2], H = pj[3];
    int ni[16] = {A.x,A.y,A.z,A.w, Bq.x,Bq.y,Bq.z,Bq.w, C.x,C.y,C.z,C.w, D.x,D.y,D.z,D.w};
    int nj[16] = {E.x,E.y,E.z,E.w, F.x,F.y,F.z,F.w, G.x,G.y,G.z,G.w, H.x,H.y,H.z,H.w};

    int mp[16];
    unsigned long long lo = 0, hi = 0;
#pragma unroll
    for (int a = 0; a < 16; ++a) {
        int r = -1;
#pragma unroll
        for (int p = 0; p < 16; ++p)
            if (nj[p] == ni[a]) r = p;
        mp[a] = r;
        unsigned long long b = (unsigned long long)(r & 0xff);
        if (a < 8) lo |= b << (8 * a); else hi |= b << (8 * (a - 8));
    }
    uint4 pk;
    pk.x = (unsigned)lo; pk.y = (unsigned)(lo >> 32);
    pk.z = (unsigned)hi; pk.w = (unsigned)(hi >> 32);
    *(uint4*)(map8 + ((size_t)idx << 4)) = pk;
    lo = 0; hi = 0;
#pragma unroll
    for (int p = 0; p < 16; ++p) {
        int r = -1;
#pragma unroll
        for (int a = 0; a < 16; ++a)
            if (ni[a] == nj[p]) r = a;
        unsigned long long b = (unsigned long long)(r & 0xff);
        if (p < 8) lo |= b << (8 * p); else hi |= b << (8 * (p - 8));
    }
    pk.x = (unsigned)lo; pk.y = (unsigned)(lo >> 32);
    pk.z = (unsigned)hi; pk.w = (unsigned)(hi >> 32);
    *(uint4*)(imp8 + ((size_t)idx << 4)) = pk;

    unsigned vm = 0;
    int a1 = -1, a2 = -1, pa1 = 0, pa2 = 0;
#pragma unroll
    for (int a = 0; a < 16; ++a) {
        if (mp[a] >= 0) {
            vm |= (1u << a);
            if (a1 < 0)      { a1 = a; pa1 = mp[a]; }
            else if (a2 < 0) { a2 = a; pa2 = mp[a]; }
        }
    }
    int ms = 0;
#pragma unroll
    for (int a = 0; a < 16; ++a)
        if (ni[a] == i) ms = a;
    int4 av;
    av.x = j;
    av.y = (a1 & 0xff) | ((pa1 & 0xff) << 8) | ((a2 & 0xff) << 16) | ((pa2 & 0xff) << 24);
    av.z = (int)(vm | ((unsigned)(mp[m] & 0xff) << 16) | ((unsigned)(ms & 0xff) << 24));
    av.w = 0;
    aux[idx] = av;
}

// ---------------------------------------------------------------------------
// Reducer tail (device fn): one block reduces g-row r and contributes
// s*fcw[r]; the 48th contribution writes out = acc + fcb.
// parts layout: slot0 [16][2048] | slot1 [16][8192] | slot2 [16][8192]
// ---------------------------------------------------------------------------
__device__ __forceinline__ void reduce_row_fin(const float* __restrict__ parts,
                                               float* __restrict__ gsum,
                                               const float* __restrict__ fcw,
                                               const float* __restrict__ fcb,
                                               float* __restrict__ out,
                                               int r, int t, float* wsum) {
    const float* p;
    int cnt4;
    if (r < 16)      { p = parts + r * 2048;                    cnt4 = 500;  }  // 2000 floats
    else if (r < 32) { p = parts + 32768 + (r - 16) * 8192;     cnt4 = 2000; }  // 8000 floats
    else             { p = parts + 163840 + (r - 32) * 8192;    cnt4 = 2000; }
    const float4* p4 = (const float4*)p;
    float s = 0.f;
    for (int n = t; n < cnt4; n += 256) {
        float4 v = p4[n];
        s += v.x + v.y + v.z + v.w;
    }
#pragma unroll
    for (int off = 32; off > 0; off >>= 1) s += __shfl_xor(s, off, 64);
    if ((t & 63) == 0) wsum[t >> 6] = s;
    __syncthreads();
    if (t == 0) {
        float tot = wsum[0] + wsum[1] + wsum[2] + wsum[3];
        atomicAdd(&gsum[0], tot * fcw[r]);           // device-scope
        __threadfence();                             // release gsum[0] add
        unsigned old = atomicAdd((unsigned*)gsum + 1, 1u);
        if (old == 47u) {
            // all 48 contributions are in coherence order before this RMW
            float acc = atomicAdd(&gsum[0], 0.0f);   // coherent read of total
            out[0] = acc + fcb[0];
        }
    }
}

// ---------------------------------------------------------------------------
// Kernel 3: one CCN step per node. chi = partial permutation =>
// T[m,a,b,c] = Fp[j, mp(a), mp(b), c].
//   S0 f32 stride-16 (self plain + sparse LDS atomics), maps A2/A4/A6/A8/A10
//   in fp8 (wave-private rows), V0 plain, V1/V2 f32 atomics.
// 18-block contraction: PRE chunks on mfma_f32_16x16x32_fp8_fp8 before
// barrier B, POST chunks (S0/V) on f16 MFMA after — both chain into the same
// fp32 accumulators (C/D layout is dtype-independent on gfx950).
// LDS total = 40960 B -> 4 blocks/CU.
// __launch_bounds__(256,3): (256,4) forced VGPR=64 -> ~170 B/thread scratch
// spills. Bound 3 lets the natural ~88-VGPR allocation through (no spills).
// DIAG=0 additionally runs the fused g-reduction tail: ticket counter at
// gsum[2]; last 48 tickets become per-row reducers (rows 32-47 spin for full
// completion; rows 0-31 come from the PREVIOUS dispatch's partials — ready).
// Deadlock-free: spinners exist only when <=15 worker blocks remain
// (32 slots in play << 1024-block residency).
// ---------------------------------------------------------------------------
template <int DIAG>
__global__ __launch_bounds__(256, 3)
void step_k(const float* __restrict__ Fp,    // (N,16,16,16) or null (DIAG)
            const float* __restrict__ Xp,    // (N,16) when DIAG
            const unsigned char* __restrict__ Wpk8s,  // this stage's fp8 B-frags (3072 B)
            const _Float16* __restrict__ Wpk16s,      // this stage's f16 B-frags (2048 h)
            const float* __restrict__ bias,  // (16)
            const signed char* __restrict__ map8,
            const signed char* __restrict__ imp8,
            const int4* __restrict__ auxp,
            float* __restrict__ Fout,        // (N,16,16,16) or null
            float* __restrict__ gp0,         // [16][2048] h-major F0 partials (DIAG)
            float* __restrict__ gp,          // [16][8192] h-major per-wave partials
            const float* __restrict__ parts, // full parts base (FIN tail)
            float* __restrict__ gsum,        // acc + counters (FIN tail)
            const float* __restrict__ fcw,
            const float* __restrict__ fcb,
            float* __restrict__ out) {
    __shared__ __attribute__((aligned(16))) float S0[16][16][16];            // 16384
    __shared__ __attribute__((aligned(16))) unsigned char MAP8[5][16][16][16];// 20480 (reused as P2 post-B)
    __shared__ __attribute__((aligned(16))) float V0f[16][16];               // 1024
    __shared__ __attribute__((aligned(16))) float V1f[16][16];               // 1024
    __shared__ __attribute__((aligned(16))) float V2f[16][16];               // 1024
    __shared__ __attribute__((aligned(16))) float S1f[16][16];               // 1024: self rowsums / Xs
    // total 40960 B -> 4 blocks/CU

    const int i = blockIdx.x;
    const int t = threadIdx.x;
    const int u = t >> 4;        // group id (= m / tile row)
    const int l = t & 15;        // lane in group (= channel)
    const int lane = t & 63, q = lane >> 4, h = lane & 15, wv = t >> 6;

    // ---- prologue: issue independent global loads ----
    int4 av = auxp[i * 16 + u];
    uint4 imv = *(const uint4*)(imp8 + ((size_t)(i * 16 + u) << 4));
    float bv = bias[l];
    const int j = av.x;
    const int a1 = (int)(signed char)(av.y & 0xff);
    const int pa1 = (av.y >> 8) & 0xff;
    const int a2 = (int)(signed char)((av.y >> 16) & 0xff);
    const int pa2 = (av.y >> 24) & 0xff;
    const unsigned vm = (unsigned)(av.z & 0xffff);
    const int pmm = (av.z >> 16) & 0xff;
    const int ms = (av.z >> 24) & 0xff;

    float frow[16], fcol[16], xv = 0.f;
    if (DIAG) {
        xv = Xp[(size_t)j * 16 + l];
    } else {
        const float* Fi = Fp + (size_t)i * 4096;
#pragma unroll
        for (int b = 0; b < 16; ++b) frow[b] = Fi[(u * 16 + b) * 16 + l];
#pragma unroll
        for (int a = 0; a < 16; ++a) fcol[a] = Fi[(a * 16 + u) * 16 + l];
    }

    // gather prefetch: rows for first (and second) valid a
    float R1[16], R2[16];
    if (!DIAG && u != ms) {
        const float* P1 = Fp + (((size_t)j * 256 + pa1 * 16) * 16) + l;
#pragma unroll
        for (int p = 0; p < 16; ++p) R1[p] = P1[p * 16];
        if (a2 >= 0) {
            const float* P2 = Fp + (((size_t)j * 256 + pa2 * 16) * 16) + l;
#pragma unroll
            for (int p = 0; p < 16; ++p) R2[p] = P2[p * 16];
        }
    }
    // B-frags: packed weights, issued pre-barrier -> stay in flight
    long Bf8[6];
    {
        const long* Wq8 = (const long*)Wpk8s;
#pragma unroll
        for (int c = 0; c < 6; ++c) Bf8[c] = Wq8[c * 64 + lane];
    }
    halfx8 Bf16[4];
    {
        const halfx8* Wq16 = (const halfx8*)Wpk16s;
#pragma unroll
        for (int c = 0; c < 4; ++c) Bf16[c] = Wq16[c * 64 + lane];
    }

    // ---- phase 1: zero MAP rows (m != ms), self-loop stores ----
    if (u != ms) {
        uint4 z = {0u, 0u, 0u, 0u};
#pragma unroll
        for (int k = 0; k < 5; ++k)
            *(uint4*)&MAP8[k][u][l][0] = z;   // fp8 row = 16 B = one uint4
    }
    if (DIAG) {
        S1f[u][l] = xv;                 // Xs staging
        V1f[u][l] = xv;
        V2f[u][l] = xv;
#pragma unroll
        for (int b = 0; b < 16; ++b) S0[u][b][l] = (b == u) ? xv : 0.f;
        unsigned char x8 = to_fp8(xv);
        MAP8[0][ms][u][l] = x8;                     // A2[ms][b=u]
        MAP8[1][ms][u][l] = x8;                     // A4[ms][a=u]
        unsigned char dz = (u == ms) ? x8 : (unsigned char)0;
        MAP8[2][ms][u][l] = dz;                     // A6[ms][b=u]
        MAP8[3][ms][u][l] = dz;                     // A8[ms][a=u]
        MAP8[4][ms][u][l] = x8;                     // A10[ms][y=u]
    } else {
        float s2 = 0.f, a10 = 0.f, a8 = 0.f;
#pragma unroll
        for (int b = 0; b < 16; ++b) {
            float v = frow[b];
            s2 += v;
            S0[u][b][l] = v;
            if (b == u)  a10 = v;       // Fi[u][u]
            if (b == ms) a8 = v;        // Fi[u][ms]
        }
        float s1 = 0.f, a6 = 0.f;
#pragma unroll
        for (int a = 0; a < 16; ++a) {
            float v = fcol[a];
            s1 += v;
            if (a == ms) a6 = v;        // Fi[ms][u]
        }
        S1f[u][l] = s2;                 // self rowsums (V0[ms] source)
        V1f[u][l] = s2;
        V2f[u][l] = s1;
        MAP8[0][ms][u][l] = to_fp8(s1);    // A2[ms][b=u]
        MAP8[1][ms][u][l] = to_fp8(s2);    // A4[ms][a=u]
        MAP8[2][ms][u][l] = to_fp8(a6);    // A6[ms][b=u]
        MAP8[3][ms][u][l] = to_fp8(a8);    // A8[ms][a=u]
        MAP8[4][ms][u][l] = to_fp8(a10);   // A10[ms][u]
    }
    LBAR();   // A

    // ---- phase 2: sparse m (group u = m); group ms does V0[ms] ----
    if (u != ms) {
        const int m = u;
        float v0acc = 0.f;
        if (DIAG) {
#pragma unroll
            for (int a = 0; a < 16; ++a) {
                if ((vm >> a) & 1u) {
                    float v = S1f[a][l];     // X[nbrs[i,a], l]
                    v0acc += v;
                    atomicAdd(&S0[a][a][l], v);
                    atomicAdd(&V1f[a][l], v);
                    atomicAdd(&V2f[a][l], v);
                    unsigned char v8 = to_fp8(v);
                    MAP8[0][m][a][l] = v8;
                    MAP8[1][m][a][l] = v8;
                    MAP8[4][m][a][l] = v8;
                    if (a == m) { MAP8[2][m][m][l] = v8; MAP8[3][m][m][l] = v8; }
                }
            }
        } else {
            float colacc[16];
#pragma unroll
            for (int p = 0; p < 16; ++p) colacc[p] = 0.f;
            auto process = [&](int a, int pa, const float (&vr)[16]) {
                float rowacc = 0.f, a8v = 0.f, a10v = 0.f;
                const bool am = (a == m);
#pragma unroll
                for (int p = 0; p < 16; ++p) {
                    float v = vr[p];
                    if (p == pmm) a8v = v;       // Fj[pa][pmm]
                    if (p == pa)  a10v = v;      // Fj[pa][pa]
                    unsigned dw = (p < 4) ? imv.x : ((p < 8) ? imv.y : ((p < 12) ? imv.z : imv.w));
                    int b = (int)(signed char)((dw >> (8 * (p & 3))) & 0xffu);
                    if (b >= 0) {
                        rowacc += v;
                        colacc[p] += v;
                        atomicAdd(&S0[a][b][l], v);
                        atomicAdd(&V2f[b][l], v);
                        if (am) MAP8[2][m][b][l] = to_fp8(v);  // A6[m][b]
                    }
                }
                v0acc += rowacc;
                atomicAdd(&V1f[a][l], rowacc);
                MAP8[1][m][a][l] = to_fp8(rowacc);   // A4
                MAP8[3][m][a][l] = to_fp8(a8v);      // A8
                MAP8[4][m][a][l] = to_fp8(a10v);     // A10
            };
            process(a1, pa1, R1);
            if (a2 >= 0) process(a2, pa2, R2);
            unsigned rm = vm & ~(1u << a1);
            if (a2 >= 0) rm &= ~(1u << a2);
            if (rm) {                    // rare tail (>2 overlaps): lazy map load
                uint4 mpq = *(const uint4*)(map8 + ((size_t)(i * 16 + u) << 4));
                do {
                    int a = __builtin_ctz(rm); rm &= rm - 1;
                    unsigned dw = (a & 8) ? ((a & 4) ? mpq.w : mpq.z) : ((a & 4) ? mpq.y : mpq.x);
                    int pa = (int)(signed char)((dw >> (8 * (a & 3))) & 0xffu);
                    float RT[16];
                    const float* P3 = Fp + (((size_t)j * 256 + pa * 16) * 16) + l;
#pragma unroll
                    for (int p = 0; p < 16; ++p) RT[p] = P3[p * 16];
                    process(a, pa, RT);
                } while (rm);
            }
#pragma unroll
            for (int p = 0; p < 16; ++p) {
                unsigned dw = (p < 4) ? imv.x : ((p < 8) ? imv.y : ((p < 12) ? imv.z : imv.w));
                int b = (int)(signed char)((dw >> (8 * (p & 3))) & 0xffu);
                if (b >= 0) MAP8[0][m][b][l] = to_fp8(colacc[p]);  // A2
            }
        }
        V0f[m][l] = v0acc;
    } else {
        float v0s = 0.f;
#pragma unroll
        for (int b = 0; b < 16; ++b) v0s += S1f[b][l];
        V0f[ms][l] = v0s;
        if (DIAG) gp0[l * 2048 + i] = v0s;   // h-major F0 g-partial
    }

    // ---- PRE-MFMAs (fp8): map chunks, wave-private rows -> no barrier ----
    floatx4 acc1[4], acc2[4];
#pragma unroll
    for (int tt = 0; tt < 4; ++tt) {
        acc1[tt] = (floatx4){0.f, 0.f, 0.f, 0.f};
        acc2[tt] = (floatx4){0.f, 0.f, 0.f, 0.f};
    }
    const int wbase = wv * 4;
    {
        const int off8 = (q & 1) * 8;
        const unsigned char* mA = (q < 2) ? &MAP8[0][0][0][0] : &MAP8[1][0][0][0];
        const unsigned char* mB = (q < 2) ? &MAP8[2][0][0][0] : &MAP8[3][0][0][0];
        const unsigned char* mC = &MAP8[4][0][0][0];
#pragma unroll
        for (int tt = 0; tt < 4; ++tt) {
            const int x = wbase + tt;
            const int base = x * 256 + h * 16 + off8;
            long f0 = *(const long*)(mA + base);
            long f1 = *(const long*)(mB + base);
            long f2 = (q < 2) ? *(const long*)(mC + base) : 0L;
            acc1[tt] = __builtin_amdgcn_mfma_f32_16x16x32_fp8_fp8(f0, Bf8[0], acc1[tt], 0, 0, 0);
            acc1[tt] = __builtin_amdgcn_mfma_f32_16x16x32_fp8_fp8(f1, Bf8[1], acc1[tt], 0, 0, 0);
            acc1[tt] = __builtin_amdgcn_mfma_f32_16x16x32_fp8_fp8(f2, Bf8[2], acc1[tt], 0, 0, 0);
            acc2[tt] = __builtin_amdgcn_mfma_f32_16x16x32_fp8_fp8(f0, Bf8[3], acc2[tt], 0, 0, 0);
            acc2[tt] = __builtin_amdgcn_mfma_f32_16x16x32_fp8_fp8(f1, Bf8[4], acc2[tt], 0, 0, 0);
            acc2[tt] = __builtin_amdgcn_mfma_f32_16x16x32_fp8_fp8(f2, Bf8[5], acc2[tt], 0, 0, 0);
        }
    }
    LBAR();   // B: S0 / V1 / V2 atomics complete; MAP8 globally dead after this

    // ---- POST-MFMAs (f16): S0 + V chunks ----
    auto cvt8a = [](const float* p) -> halfx8 {  // 16B-aligned f32 -> f16x8
        float4 va = *(const float4*)p, vb = *(const float4*)(p + 4);
        halfx8 r;
        r[0] = (_Float16)va.x; r[1] = (_Float16)va.y; r[2] = (_Float16)va.z; r[3] = (_Float16)va.w;
        r[4] = (_Float16)vb.x; r[5] = (_Float16)vb.y; r[6] = (_Float16)vb.z; r[7] = (_Float16)vb.w;
        return r;
    };
#pragma unroll
    for (int tt = 0; tt < 4; ++tt) {
        const int x = wbase + tt;
        halfx8 p3, p4;
        if (q < 2) {
            p3 = cvt8a(&S0[x][h][q * 8]);                // S0 (blk0/1)
            p4 = cvt8a(&V1f[x][q * 8]);                  // V1 (blk14/15)
        } else {
            const int c0 = (q - 2) * 8;
            p3 = cvt8a(&V0f[x][c0]);                     // V0 (blk12/13)
            p4 = cvt8a(&V2f[x][c0]);                     // V2 (blk16/17)
        }
        acc1[tt] = __builtin_amdgcn_mfma_f32_16x16x32_f16(p3, Bf16[0], acc1[tt], 0, 0, 0);
        acc1[tt] = __builtin_amdgcn_mfma_f32_16x16x32_f16(p4, Bf16[1], acc1[tt], 0, 0, 0);
        acc2[tt] = __builtin_amdgcn_mfma_f32_16x16x32_f16(p3, Bf16[2], acc2[tt], 0, 0, 0);
        acc2[tt] = __builtin_amdgcn_mfma_f32_16x16x32_f16(p4, Bf16[3], acc2[tt], 0, 0, 0);
    }

    // ---- transpose ACC2 through the (dead) MAP8 region; writes need no
    //      barrier (all MAP8 reads completed before barrier B) ----
    float* P2f = (float*)&MAP8[0][0][0][0];   // [r][s][h] stride 17 (17408 B <= 20480)
#pragma unroll
    for (int tt = 0; tt < 4; ++tt) {
        const int x = wbase + tt;
#pragma unroll
        for (int r = 0; r < 4; ++r)
            P2f[(x * 16 + (q * 4 + r)) * 17 + h] = acc2[tt][r];
    }
    LBAR();   // C

    // ---- epilogue: combine, relu, store; per-wave g-partials ----
    float gpart = 0.f;
#pragma unroll
    for (int tt = 0; tt < 4; ++tt) {
        const int x = wbase + tt;
#pragma unroll
        for (int r = 0; r < 4; ++r) {
            const int y = q * 4 + r;
            float val = acc1[tt][r] + P2f[(y * 16 + x) * 17 + h] + bv;
            val = fmaxf(val, 0.f);
            gpart += val;
            if (Fout) Fout[(size_t)i * 4096 + (x * 16 + y) * 16 + h] = val;
        }
    }
    gpart += __shfl_xor(gpart, 16, 64);
    gpart += __shfl_xor(gpart, 32, 64);
    if (lane < 16) gp[h * 8192 + i * 4 + wv] = gpart;   // h-major

    // ---- fused g-reduction tail (final step only) ----
    if (!DIAG) {
        __shared__ int tk_sh;
        __shared__ float wsum[4];
        __syncthreads();                       // all waves' gp stores issued
        if (t == 0) {
            __threadfence();                   // release gp stores device-scope
            tk_sh = (int)atomicAdd((unsigned*)gsum + 2, 1u);  // ticket
        }
        __syncthreads();
        int tk = tk_sh;
        if (tk < NN - 48) return;              // not a reducer
        int r = tk - (NN - 48);                // 0..47; r>=32 <=> last 16 tickets
        if (r >= 32) {
            // F2 rows: need ALL step<0> blocks done. At ticket NN-16, <=15
            // worker blocks remain (all resident) -> spin is safe and short.
            if (t == 0) {
                while (atomicAdd((unsigned*)gsum + 2, 0u) < (unsigned)NN)
                    __builtin_amdgcn_s_sleep(8);
                __threadfence();               // acquire all gp stores
            }
            __syncthreads();
        }
        reduce_row_fin(parts, gsum, fcw, fcb, out, r, t, wsum);
    }
}

extern "C" void kernel_launch(void* const* d_in, const int* in_sizes, int n_in,
                              void* d_out, int out_size, void* d_ws, size_t ws_size,
                              hipStream_t stream) {
    const float* X   = (const float*)d_in[0];
    const float* adj = (const float*)d_in[1];
    const float* W1  = (const float*)d_in[2];
    const float* b1  = (const float*)d_in[3];
    const float* W2  = (const float*)d_in[4];
    const float* b2  = (const float*)d_in[5];
    const float* fcw = (const float*)d_in[6];
    const float* fcb = (const float*)d_in[7];
    float* out = (float*)d_out;
    char* ws = (char*)d_ws;

    // workspace layout (16B-aligned):
    float*         gsum  = (float*)(ws + 0);               // 192 B (acc + counters)
    int*           nbrs  = (int*)(ws + 1024);              // 128000 B
    signed char*   map8  = (signed char*)(ws + 129280);    // 512000 B
    signed char*   imp8  = (signed char*)(ws + 641280);    // 512000 B
    int4*          aux   = (int4*)(ws + 1153280);          // 512000 B
    float*         parts = (float*)(ws + 1665280);         // 1179648 B
    unsigned char* Wpk8  = (unsigned char*)(ws + 2844928); // 6144 B
    _Float16*      Wpk16 = (_Float16*)(ws + 2851072);      // 8192 B
    float*         F1    = (float*)(ws + 2859264);         // 32768000 B (~35.6 MB total)

    build_nbrs_k<<<NN, 64, 0, stream>>>(adj, nbrs, gsum);
    build_map_prep_k<<<165, 256, 0, stream>>>(nbrs, map8, imp8, aux, W1, W2, Wpk8, Wpk16);
    // parts: slot0 = F0 [16][2048] | slot1 = F1 [16][8192] | slot2 = F2 [16][8192]
    step_k<1><<<NN, 256, 0, stream>>>(nullptr, X, Wpk8, Wpk16, b1, map8, imp8, aux, F1,
                                      parts, parts + 32768,
                                      nullptr, nullptr, nullptr, nullptr, nullptr);
    step_k<0><<<NN, 256, 0, stream>>>(F1, X, Wpk8 + 3072, Wpk16 + 2048, b2, map8, imp8, aux,
                                      nullptr, nullptr, parts + 163840,
                                      parts, gsum, fcw, fcb, out);
}

// Round 6
// 203.692 us; speedup vs baseline: 1.0070x; 1.0070x over previous
//
#include <hip/hip_runtime.h>

#define NN 2000

typedef _Float16 halfx8 __attribute__((ext_vector_type(8)));
typedef float floatx4 __attribute__((ext_vector_type(4)));

// lgkm-only barrier: LDS visibility without draining vmcnt (global loads stay
// in flight across phase boundaries). "memory" clobber pins compiler ordering.
#define LBAR() asm volatile("s_waitcnt lgkmcnt(0)\n\ts_barrier" ::: "memory")

// f32 -> OCP fp8 e4m3 (gfx950 HW convert; same format the fp8 MFMA consumes)
__device__ __forceinline__ unsigned char to_fp8(float v) {
    return (unsigned char)(__builtin_amdgcn_cvt_pk_fp8_f32(v, 0.f, 0, false) & 0xff);
}

// ---------------------------------------------------------------------------
// Kernel 1: sorted neighbor lists. float4 adj loads (4x fewer VMEM issues than
// scalar), 4-ballot prefix scan per 256-col chunk. Also zero-inits the fused
// finalize accumulator + both counters (stream-ordered ahead of use).
// ---------------------------------------------------------------------------
__global__ void build_nbrs_k(const float* __restrict__ adj,
                             int* __restrict__ nbrs,
                             float* __restrict__ gsum) {
    int i = blockIdx.x;
    int lane = threadIdx.x;
    if (i == 0 && lane == 0) {
        gsum[0] = 0.0f;                      // fused-finalize accumulator
        ((unsigned*)gsum)[1] = 0u;           // finalize contribution counter
        ((unsigned*)gsum)[2] = 0u;           // step<0> completion/ticket counter
    }
    const float4* row = (const float4*)(adj + (size_t)i * NN);  // 500 float4s
    float4 v[8];
#pragma unroll
    for (int c = 0; c < 8; ++c) {
        int idx4 = c * 64 + lane;
        if (idx4 < 500) v[c] = row[idx4];
        else            v[c] = make_float4(0.f, 0.f, 0.f, 0.f);
    }
    int base = 0;
#pragma unroll
    for (int c = 0; c < 8; ++c) {
        unsigned nib = (v[c].x > 0.5f ? 1u : 0u) | (v[c].y > 0.5f ? 2u : 0u) |
                       (v[c].z > 0.5f ? 4u : 0u) | (v[c].w > 0.5f ? 8u : 0u);
        unsigned long long b0 = __ballot(nib & 1u);
        unsigned long long b1 = __ballot(nib & 2u);
        unsigned long long b2 = __ballot(nib & 4u);
        unsigned long long b3 = __ballot(nib & 8u);
        unsigned long long below = (1ull << lane) - 1ull;
        int pos = base + __popcll(b0 & below) + __popcll(b1 & below) +
                         __popcll(b2 & below) + __popcll(b3 & below);
        int col0 = c * 256 + lane * 4;
        if (nib & 1u) { nbrs[i * 16 + pos] = col0;     ++pos; }
        if (nib & 2u) { nbrs[i * 16 + pos] = col0 + 1; ++pos; }
        if (nib & 4u) { nbrs[i * 16 + pos] = col0 + 2; ++pos; }
        if (nib & 8u) { nbrs[i * 16 + pos] = col0 + 3; ++pos; }
        base += __popcll(b0) + __popcll(b1) + __popcll(b2) + __popcll(b3);
    }
}

// ---------------------------------------------------------------------------
// Kernel 2 (fused): per-(i,m) maps + aux descriptor (blocks 0..124) and
// W1/W2 MFMA B-fragment packing (blocks 125..164).
//   map8[i][m][a] = p : nbrs[j][p]==nbrs[i][a] (or -1), j=nbrs[i][m]
//   imp8[i][m][p] = a (inverse, or -1)
//   aux = { j,  a1|pa1<<8|a2<<16|pa2<<24,  vm|pmm<<16|ms<<24, 0 }
// PRE chunks (maps, fp8 e4m3): c0=(blk2|blk4) c1=(blk6|blk8) c2=(blk10|-)
//   for ACC1; c3=(3|5) c4=(7|9) c5=(11|-) for ACC2.  (k<16 -> first blk)
// POST chunks (S0/V, f16): d0=(blk0|blk12) d1=(blk14|blk16) ACC1;
//   d2=(1|13) d3=(15|17) ACC2.
// B-frag: lane L holds B[k=(L>>4)*8+j][n=L&15].
// ---------------------------------------------------------------------------
__global__ void build_map_prep_k(const int* __restrict__ nbrs,
                                 signed char* __restrict__ map8,
                                 signed char* __restrict__ imp8,
                                 int4* __restrict__ aux,
                                 const float* __restrict__ W1,
                                 const float* __restrict__ W2,
                                 unsigned char* __restrict__ Wpk8,
                                 _Float16* __restrict__ Wpk16) {
    if (blockIdx.x >= 125) {
        // ---- weight-packing part ----
        int idx = (blockIdx.x - 125) * 256 + threadIdx.x;
        if (idx >= 10240) return;
        if (idx < 6144) {            // fp8 PRE: [2][6][64][8] bytes
            int stage = idx / 3072;
            int r = idx % 3072;
            int c = r / 512;
            int r2 = r % 512;
            int L = r2 >> 3, jj = r2 & 7;
            int q = L >> 4, h = L & 15;
            int k = q * 8 + jj;
            const int bA[6] = {2, 6, 10, 3, 7, 11};
            const int bB[6] = {4, 8, -1, 5, 9, -1};
            int tb = (k < 16) ? bA[c] : bB[c];
            int ci = k & 15;
            const float* W = stage ? W2 : W1;
            float val = (tb < 0) ? 0.f : W[h * 288 + tb * 16 + ci];
            Wpk8[idx] = to_fp8(val);
        } else {                     // f16 POST: [2][4][64][8] halves
            int id2 = idx - 6144;
            int stage = id2 / 2048;
            int r = id2 % 2048;
            int c = r / 512;
            int r2 = r % 512;
            int L = r2 >> 3, jj = r2 & 7;
            int q = L >> 4, h = L & 15;
            int k = q * 8 + jj;
            const int bA[4] = {0, 14, 1, 15};
            const int bB[4] = {12, 16, 13, 17};
            int tb = (k < 16) ? bA[c] : bB[c];
            int ci = k & 15;
            const float* W = stage ? W2 : W1;
            float val = W[h * 288 + tb * 16 + ci];
            Wpk16[id2] = (_Float16)val;
        }
        return;
    }
    // ---- map-building part ----
    int idx = blockIdx.x * 256 + threadIdx.x;  // (i,m)
    if (idx >= NN * 16) return;
    int i = idx >> 4;
    int m = idx & 15;
    int j = nbrs[idx];
    const int4* pi = (const int4*)(nbrs + (size_t)i * 16);
    const int4* pj = (const int4*)(nbrs + (size_t)j * 16);
    int4 A = pi[0], Bq = pi[1], C = pi[2], D = pi[3];
    int4 E = pj[0], F = pj[1], G = pj[2], H = pj[3];
    int ni[16] = {A.x,A.y,A.z,A.w, Bq.x,Bq.y,Bq.z,Bq.w, C.x,C.y,C.z,C.w, D.x,D.y,D.z,D.w};
    int nj[16] = {E.x,E.y,E.z,E.w, F.x,F.y,F.z,F.w, G.x,G.y,G.z,G.w, H.x,H.y,H.z,H.w};

    int mp[16];
    unsigned long long lo = 0, hi = 0;
#pragma unroll
    for (int a = 0; a < 16; ++a) {
        int r = -1;
#pragma unroll
        for (int p = 0; p < 16; ++p)
            if (nj[p] == ni[a]) r = p;
        mp[a] = r;
        unsigned long long b = (unsigned long long)(r & 0xff);
        if (a < 8) lo |= b << (8 * a); else hi |= b << (8 * (a - 8));
    }
    uint4 pk;
    pk.x = (unsigned)lo; pk.y = (unsigned)(lo >> 32);
    pk.z = (unsigned)hi; pk.w = (unsigned)(hi >> 32);
    *(uint4*)(map8 + ((size_t)idx << 4)) = pk;
    lo = 0; hi = 0;
#pragma unroll
    for (int p = 0; p < 16; ++p) {
        int r = -1;
#pragma unroll
        for (int a = 0; a < 16; ++a)
            if (ni[a] == nj[p]) r = a;
        unsigned long long b = (unsigned long long)(r & 0xff);
        if (p < 8) lo |= b << (8 * p); else hi |= b << (8 * (p - 8));
    }
    pk.x = (unsigned)lo; pk.y = (unsigned)(lo >> 32);
    pk.z = (unsigned)hi; pk.w = (unsigned)(hi >> 32);
    *(uint4*)(imp8 + ((size_t)idx << 4)) = pk;

    unsigned vm = 0;
    int a1 = -1, a2 = -1, pa1 = 0, pa2 = 0;
#pragma unroll
    for (int a = 0; a < 16; ++a) {
        if (mp[a] >= 0) {
            vm |= (1u << a);
            if (a1 < 0)      { a1 = a; pa1 = mp[a]; }
            else if (a2 < 0) { a2 = a; pa2 = mp[a]; }
        }
    }
    int ms = 0;
#pragma unroll
    for (int a = 0; a < 16; ++a)
        if (ni[a] == i) ms = a;
    int4 av;
    av.x = j;
    av.y = (a1 & 0xff) | ((pa1 & 0xff) << 8) | ((a2 & 0xff) << 16) | ((pa2 & 0xff) << 24);
    av.z = (int)(vm | ((unsigned)(mp[m] & 0xff) << 16) | ((unsigned)(ms & 0xff) << 24));
    av.w = 0;
    aux[idx] = av;
}

// ---------------------------------------------------------------------------
// Reducer tail (device fn): one block reduces g-row r and contributes
// s*fcw[r]; the 48th contribution writes out = acc + fcb.
// parts layout: slot0 [16][2048] | slot1 [16][8192] | slot2 [16][8192]
// wsum points into DEAD LDS (S1f) — no extra LDS allocation.
// ---------------------------------------------------------------------------
__device__ __forceinline__ void reduce_row_fin(const float* __restrict__ parts,
                                               float* __restrict__ gsum,
                                               const float* __restrict__ fcw,
                                               const float* __restrict__ fcb,
                                               float* __restrict__ out,
                                               int r, int t, float* wsum) {
    const float* p;
    int cnt4;
    if (r < 16)      { p = parts + r * 2048;                    cnt4 = 500;  }  // 2000 floats
    else if (r < 32) { p = parts + 32768 + (r - 16) * 8192;     cnt4 = 2000; }  // 8000 floats
    else             { p = parts + 163840 + (r - 32) * 8192;    cnt4 = 2000; }
    const float4* p4 = (const float4*)p;
    float s = 0.f;
    for (int n = t; n < cnt4; n += 256) {
        float4 v = p4[n];
        s += v.x + v.y + v.z + v.w;
    }
#pragma unroll
    for (int off = 32; off > 0; off >>= 1) s += __shfl_xor(s, off, 64);
    if ((t & 63) == 0) wsum[t >> 6] = s;
    __syncthreads();
    if (t == 0) {
        float tot = wsum[0] + wsum[1] + wsum[2] + wsum[3];
        atomicAdd(&gsum[0], tot * fcw[r]);           // device-scope
        __threadfence();                             // release gsum[0] add
        unsigned old = atomicAdd((unsigned*)gsum + 1, 1u);
        if (old == 47u) {
            // all 48 contributions are in coherence order before this RMW
            float acc = atomicAdd(&gsum[0], 0.0f);   // coherent read of total
            out[0] = acc + fcb[0];
        }
    }
}

// ---------------------------------------------------------------------------
// Kernel 3: one CCN step per node. chi = partial permutation =>
// T[m,a,b,c] = Fp[j, mp(a), mp(b), c].
//   S0 f32 stride-16 (self plain + sparse LDS atomics), maps A2/A4/A6/A8/A10
//   in fp8 (wave-private rows), V0 plain, V1/V2 f32 atomics.
// 18-block contraction: PRE chunks on mfma_f32_16x16x32_fp8_fp8 before
// barrier B, POST chunks (S0/V) on f16 MFMA after — both chain into the same
// fp32 accumulators (C/D layout is dtype-independent on gfx950).
// LDS total = 40960 B EXACTLY -> 4 blocks/CU. The R3 regression was +512 B of
// tail scratch LDS (41472) dropping residency to 3 blocks/CU (-40% perf on a
// latency-bound kernel). Tail scratch now aliases dead S1f — NO new LDS.
// __launch_bounds__(256,3): (256,4) forced VGPR=64 -> scratch spills.
// DIAG=0 runs the fused g-reduction tail: ticket counter at gsum[2]; last 48
// tickets become per-row reducers (rows 32-47 spin for full completion; rows
// 0-31 are previous-dispatch partials — ready). Deadlock-free: spinners exist
// only when <=16 worker blocks remain (<< 1024-block residency). tk>=NN guard
// makes rocprof counter-replay (stale ticket counter) safe.
// ---------------------------------------------------------------------------
template <int DIAG>
__global__ __launch_bounds__(256, 3)
void step_k(const float* __restrict__ Fp,    // (N,16,16,16) or null (DIAG)
            const float* __restrict__ Xp,    // (N,16) when DIAG
            const unsigned char* __restrict__ Wpk8s,  // this stage's fp8 B-frags (3072 B)
            const _Float16* __restrict__ Wpk16s,      // this stage's f16 B-frags (2048 h)
            const float* __restrict__ bias,  // (16)
            const signed char* __restrict__ map8,
            const signed char* __restrict__ imp8,
            const int4* __restrict__ auxp,
            float* __restrict__ Fout,        // (N,16,16,16) or null
            float* __restrict__ gp0,         // [16][2048] h-major F0 partials (DIAG)
            float* __restrict__ gp,          // [16][8192] h-major per-wave partials
            const float* __restrict__ parts, // full parts base (FIN tail)
            float* __restrict__ gsum,        // acc + counters (FIN tail)
            const float* __restrict__ fcw,
            const float* __restrict__ fcb,
            float* __restrict__ out) {
    __shared__ __attribute__((aligned(16))) float S0[16][16][16];            // 16384
    __shared__ __attribute__((aligned(16))) unsigned char MAP8[5][16][16][16];// 20480 (reused as P2 post-B)
    __shared__ __attribute__((aligned(16))) float V0f[16][16];               // 1024
    __shared__ __attribute__((aligned(16))) float V1f[16][16];               // 1024
    __shared__ __attribute__((aligned(16))) float V2f[16][16];               // 1024
    __shared__ __attribute__((aligned(16))) float S1f[16][16];               // 1024: self rowsums / Xs; tail scratch post-C
    // total 40960 B -> 4 blocks/CU

    const int i = blockIdx.x;
    const int t = threadIdx.x;
    const int u = t >> 4;        // group id (= m / tile row)
    const int l = t & 15;        // lane in group (= channel)
    const int lane = t & 63, q = lane >> 4, h = lane & 15, wv = t >> 6;

    // ---- prologue: issue independent global loads ----
    int4 av = auxp[i * 16 + u];
    uint4 imv = *(const uint4*)(imp8 + ((size_t)(i * 16 + u) << 4));
    float bv = bias[l];
    const int j = av.x;
    const int a1 = (int)(signed char)(av.y & 0xff);
    const int pa1 = (av.y >> 8) & 0xff;
    const int a2 = (int)(signed char)((av.y >> 16) & 0xff);
    const int pa2 = (av.y >> 24) & 0xff;
    const unsigned vm = (unsigned)(av.z & 0xffff);
    const int pmm = (av.z >> 16) & 0xff;
    const int ms = (av.z >> 24) & 0xff;

    float frow[16], fcol[16], xv = 0.f;
    if (DIAG) {
        xv = Xp[(size_t)j * 16 + l];
    } else {
        const float* Fi = Fp + (size_t)i * 4096;
#pragma unroll
        for (int b = 0; b < 16; ++b) frow[b] = Fi[(u * 16 + b) * 16 + l];
#pragma unroll
        for (int a = 0; a < 16; ++a) fcol[a] = Fi[(a * 16 + u) * 16 + l];
    }

    // gather prefetch: rows for first (and second) valid a
    float R1[16], R2[16];
    if (!DIAG && u != ms) {
        const float* P1 = Fp + (((size_t)j * 256 + pa1 * 16) * 16) + l;
#pragma unroll
        for (int p = 0; p < 16; ++p) R1[p] = P1[p * 16];
        if (a2 >= 0) {
            const float* P2 = Fp + (((size_t)j * 256 + pa2 * 16) * 16) + l;
#pragma unroll
            for (int p = 0; p < 16; ++p) R2[p] = P2[p * 16];
        }
    }
    // B-frags: packed weights, issued pre-barrier -> stay in flight
    long Bf8[6];
    {
        const long* Wq8 = (const long*)Wpk8s;
#pragma unroll
        for (int c = 0; c < 6; ++c) Bf8[c] = Wq8[c * 64 + lane];
    }
    halfx8 Bf16[4];
    {
        const halfx8* Wq16 = (const halfx8*)Wpk16s;
#pragma unroll
        for (int c = 0; c < 4; ++c) Bf16[c] = Wq16[c * 64 + lane];
    }

    // ---- phase 1: zero MAP rows (m != ms), self-loop stores ----
    if (u != ms) {
        uint4 z = {0u, 0u, 0u, 0u};
#pragma unroll
        for (int k = 0; k < 5; ++k)
            *(uint4*)&MAP8[k][u][l][0] = z;   // fp8 row = 16 B = one uint4
    }
    if (DIAG) {
        S1f[u][l] = xv;                 // Xs staging
        V1f[u][l] = xv;
        V2f[u][l] = xv;
#pragma unroll
        for (int b = 0; b < 16; ++b) S0[u][b][l] = (b == u) ? xv : 0.f;
        unsigned char x8 = to_fp8(xv);
        MAP8[0][ms][u][l] = x8;                     // A2[ms][b=u]
        MAP8[1][ms][u][l] = x8;                     // A4[ms][a=u]
        unsigned char dz = (u == ms) ? x8 : (unsigned char)0;
        MAP8[2][ms][u][l] = dz;                     // A6[ms][b=u]
        MAP8[3][ms][u][l] = dz;                     // A8[ms][a=u]
        MAP8[4][ms][u][l] = x8;                     // A10[ms][y=u]
    } else {
        float s2 = 0.f, a10 = 0.f, a8 = 0.f;
#pragma unroll
        for (int b = 0; b < 16; ++b) {
            float v = frow[b];
            s2 += v;
            S0[u][b][l] = v;
            if (b == u)  a10 = v;       // Fi[u][u]
            if (b == ms) a8 = v;        // Fi[u][ms]
        }
        float s1 = 0.f, a6 = 0.f;
#pragma unroll
        for (int a = 0; a < 16; ++a) {
            float v = fcol[a];
            s1 += v;
            if (a == ms) a6 = v;        // Fi[ms][u]
        }
        S1f[u][l] = s2;                 // self rowsums (V0[ms] source)
        V1f[u][l] = s2;
        V2f[u][l] = s1;
        MAP8[0][ms][u][l] = to_fp8(s1);    // A2[ms][b=u]
        MAP8[1][ms][u][l] = to_fp8(s2);    // A4[ms][a=u]
        MAP8[2][ms][u][l] = to_fp8(a6);    // A6[ms][b=u]
        MAP8[3][ms][u][l] = to_fp8(a8);    // A8[ms][a=u]
        MAP8[4][ms][u][l] = to_fp8(a10);   // A10[ms][u]
    }
    LBAR();   // A

    // ---- phase 2: sparse m (group u = m); group ms does V0[ms] ----
    if (u != ms) {
        const int m = u;
        float v0acc = 0.f;
        if (DIAG) {
#pragma unroll
            for (int a = 0; a < 16; ++a) {
                if ((vm >> a) & 1u) {
                    float v = S1f[a][l];     // X[nbrs[i,a], l]
                    v0acc += v;
                    atomicAdd(&S0[a][a][l], v);
                    atomicAdd(&V1f[a][l], v);
                    atomicAdd(&V2f[a][l], v);
                    unsigned char v8 = to_fp8(v);
                    MAP8[0][m][a][l] = v8;
                    MAP8[1][m][a][l] = v8;
                    MAP8[4][m][a][l] = v8;
                    if (a == m) { MAP8[2][m][m][l] = v8; MAP8[3][m][m][l] = v8; }
                }
            }
        } else {
            float colacc[16];
#pragma unroll
            for (int p = 0; p < 16; ++p) colacc[p] = 0.f;
            auto process = [&](int a, int pa, const float (&vr)[16]) {
                float rowacc = 0.f, a8v = 0.f, a10v = 0.f;
                const bool am = (a == m);
#pragma unroll
                for (int p = 0; p < 16; ++p) {
                    float v = vr[p];
                    if (p == pmm) a8v = v;       // Fj[pa][pmm]
                    if (p == pa)  a10v = v;      // Fj[pa][pa]
                    unsigned dw = (p < 4) ? imv.x : ((p < 8) ? imv.y : ((p < 12) ? imv.z : imv.w));
                    int b = (int)(signed char)((dw >> (8 * (p & 3))) & 0xffu);
                    if (b >= 0) {
                        rowacc += v;
                        colacc[p] += v;
                        atomicAdd(&S0[a][b][l], v);
                        atomicAdd(&V2f[b][l], v);
                        if (am) MAP8[2][m][b][l] = to_fp8(v);  // A6[m][b]
                    }
                }
                v0acc += rowacc;
                atomicAdd(&V1f[a][l], rowacc);
                MAP8[1][m][a][l] = to_fp8(rowacc);   // A4
                MAP8[3][m][a][l] = to_fp8(a8v);      // A8
                MAP8[4][m][a][l] = to_fp8(a10v);     // A10
            };
            process(a1, pa1, R1);
            if (a2 >= 0) process(a2, pa2, R2);
            unsigned rm = vm & ~(1u << a1);
            if (a2 >= 0) rm &= ~(1u << a2);
            if (rm) {                    // rare tail (>2 overlaps): lazy map load
                uint4 mpq = *(const uint4*)(map8 + ((size_t)(i * 16 + u) << 4));
                do {
                    int a = __builtin_ctz(rm); rm &= rm - 1;
                    unsigned dw = (a & 8) ? ((a & 4) ? mpq.w : mpq.z) : ((a & 4) ? mpq.y : mpq.x);
                    int pa = (int)(signed char)((dw >> (8 * (a & 3))) & 0xffu);
                    float RT[16];
                    const float* P3 = Fp + (((size_t)j * 256 + pa * 16) * 16) + l;
#pragma unroll
                    for (int p = 0; p < 16; ++p) RT[p] = P3[p * 16];
                    process(a, pa, RT);
                } while (rm);
            }
#pragma unroll
            for (int p = 0; p < 16; ++p) {
                unsigned dw = (p < 4) ? imv.x : ((p < 8) ? imv.y : ((p < 12) ? imv.z : imv.w));
                int b = (int)(signed char)((dw >> (8 * (p & 3))) & 0xffu);
                if (b >= 0) MAP8[0][m][b][l] = to_fp8(colacc[p]);  // A2
            }
        }
        V0f[m][l] = v0acc;
    } else {
        float v0s = 0.f;
#pragma unroll
        for (int b = 0; b < 16; ++b) v0s += S1f[b][l];
        V0f[ms][l] = v0s;
        if (DIAG) gp0[l * 2048 + i] = v0s;   // h-major F0 g-partial
    }

    // ---- PRE-MFMAs (fp8): map chunks, wave-private rows -> no barrier ----
    floatx4 acc1[4], acc2[4];
#pragma unroll
    for (int tt = 0; tt < 4; ++tt) {
        acc1[tt] = (floatx4){0.f, 0.f, 0.f, 0.f};
        acc2[tt] = (floatx4){0.f, 0.f, 0.f, 0.f};
    }
    const int wbase = wv * 4;
    {
        const int off8 = (q & 1) * 8;
        const unsigned char* mA = (q < 2) ? &MAP8[0][0][0][0] : &MAP8[1][0][0][0];
        const unsigned char* mB = (q < 2) ? &MAP8[2][0][0][0] : &MAP8[3][0][0][0];
        const unsigned char* mC = &MAP8[4][0][0][0];
#pragma unroll
        for (int tt = 0; tt < 4; ++tt) {
            const int x = wbase + tt;
            const int base = x * 256 + h * 16 + off8;
            long f0 = *(const long*)(mA + base);
            long f1 = *(const long*)(mB + base);
            long f2 = (q < 2) ? *(const long*)(mC + base) : 0L;
            acc1[tt] = __builtin_amdgcn_mfma_f32_16x16x32_fp8_fp8(f0, Bf8[0], acc1[tt], 0, 0, 0);
            acc1[tt] = __builtin_amdgcn_mfma_f32_16x16x32_fp8_fp8(f1, Bf8[1], acc1[tt], 0, 0, 0);
            acc1[tt] = __builtin_amdgcn_mfma_f32_16x16x32_fp8_fp8(f2, Bf8[2], acc1[tt], 0, 0, 0);
            acc2[tt] = __builtin_amdgcn_mfma_f32_16x16x32_fp8_fp8(f0, Bf8[3], acc2[tt], 0, 0, 0);
            acc2[tt] = __builtin_amdgcn_mfma_f32_16x16x32_fp8_fp8(f1, Bf8[4], acc2[tt], 0, 0, 0);
            acc2[tt] = __builtin_amdgcn_mfma_f32_16x16x32_fp8_fp8(f2, Bf8[5], acc2[tt], 0, 0, 0);
        }
    }
    LBAR();   // B: S0 / V1 / V2 atomics complete; MAP8 + S1f globally dead after this

    // ---- POST-MFMAs (f16): S0 + V chunks ----
    auto cvt8a = [](const float* p) -> halfx8 {  // 16B-aligned f32 -> f16x8
        float4 va = *(const float4*)p, vb = *(const float4*)(p + 4);
        halfx8 r;
        r[0] = (_Float16)va.x; r[1] = (_Float16)va.y; r[2] = (_Float16)va.z; r[3] = (_Float16)va.w;
        r[4] = (_Float16)vb.x; r[5] = (_Float16)vb.y; r[6] = (_Float16)vb.z; r[7] = (_Float16)vb.w;
        return r;
    };
#pragma unroll
    for (int tt = 0; tt < 4; ++tt) {
        const int x = wbase + tt;
        halfx8 p3, p4;
        if (q < 2) {
            p3 = cvt8a(&S0[x][h][q * 8]);                // S0 (blk0/1)
            p4 = cvt8a(&V1f[x][q * 8]);                  // V1 (blk14/15)
        } else {
            const int c0 = (q - 2) * 8;
            p3 = cvt8a(&V0f[x][c0]);                     // V0 (blk12/13)
            p4 = cvt8a(&V2f[x][c0]);                     // V2 (blk16/17)
        }
        acc1[tt] = __builtin_amdgcn_mfma_f32_16x16x32_f16(p3, Bf16[0], acc1[tt], 0, 0, 0);
        acc1[tt] = __builtin_amdgcn_mfma_f32_16x16x32_f16(p4, Bf16[1], acc1[tt], 0, 0, 0);
        acc2[tt] = __builtin_amdgcn_mfma_f32_16x16x32_f16(p3, Bf16[2], acc2[tt], 0, 0, 0);
        acc2[tt] = __builtin_amdgcn_mfma_f32_16x16x32_f16(p4, Bf16[3], acc2[tt], 0, 0, 0);
    }

    // ---- transpose ACC2 through the (dead) MAP8 region; writes need no
    //      barrier (all MAP8 reads completed before barrier B) ----
    float* P2f = (float*)&MAP8[0][0][0][0];   // [r][s][h] stride 17 (17408 B <= 20480)
#pragma unroll
    for (int tt = 0; tt < 4; ++tt) {
        const int x = wbase + tt;
#pragma unroll
        for (int r = 0; r < 4; ++r)
            P2f[(x * 16 + (q * 4 + r)) * 17 + h] = acc2[tt][r];
    }
    LBAR();   // C

    // ---- epilogue: combine, relu, store; per-wave g-partials ----
    float gpart = 0.f;
#pragma unroll
    for (int tt = 0; tt < 4; ++tt) {
        const int x = wbase + tt;
#pragma unroll
        for (int r = 0; r < 4; ++r) {
            const int y = q * 4 + r;
            float val = acc1[tt][r] + P2f[(y * 16 + x) * 17 + h] + bv;
            val = fmaxf(val, 0.f);
            gpart += val;
            if (Fout) Fout[(size_t)i * 4096 + (x * 16 + y) * 16 + h] = val;
        }
    }
    gpart += __shfl_xor(gpart, 16, 64);
    gpart += __shfl_xor(gpart, 32, 64);
    if (lane < 16) gp[h * 8192 + i * 4 + wv] = gpart;   // h-major

    // ---- fused g-reduction tail (final step only); scratch in dead S1f ----
    if (!DIAG) {
        float* wsum  = &S1f[0][0];         // 16 B of dead LDS
        int*   tk_sh = (int*)&S1f[1][0];   // 4 B of dead LDS
        __syncthreads();                   // all gp stores issued; S1f reusable
        if (t == 0) {
            __threadfence();               // release gp stores device-scope
            *tk_sh = (int)atomicAdd((unsigned*)gsum + 2, 1u);  // ticket
        }
        __syncthreads();
        int tk = *tk_sh;
        if (tk < NN - 48 || tk >= NN) return;  // not a reducer (tk>=NN: replay guard)
        int r = tk - (NN - 48);            // 0..47; r>=32 <=> last 16 tickets
        if (r >= 32) {
            // F2 rows: need ALL step<0> blocks done. At ticket NN-16, <=15
            // worker blocks remain (all resident) -> spin is safe and short.
            if (t == 0) {
                while (atomicAdd((unsigned*)gsum + 2, 0u) < (unsigned)NN)
                    __builtin_amdgcn_s_sleep(8);
                __threadfence();           // acquire all gp stores
            }
            __syncthreads();
        }
        reduce_row_fin(parts, gsum, fcw, fcb, out, r, t, wsum);
    }
}

extern "C" void kernel_launch(void* const* d_in, const int* in_sizes, int n_in,
                              void* d_out, int out_size, void* d_ws, size_t ws_size,
                              hipStream_t stream) {
    const float* X   = (const float*)d_in[0];
    const float* adj = (const float*)d_in[1];
    const float* W1  = (const float*)d_in[2];
    const float* b1  = (const float*)d_in[3];
    const float* W2  = (const float*)d_in[4];
    const float* b2  = (const float*)d_in[5];
    const float* fcw = (const float*)d_in[6];
    const float* fcb = (const float*)d_in[7];
    float* out = (float*)d_out;
    char* ws = (char*)d_ws;

    // workspace layout (16B-aligned):
    float*         gsum  = (float*)(ws + 0);               // 192 B (acc + counters)
    int*           nbrs  = (int*)(ws + 1024);              // 128000 B
    signed char*   map8  = (signed char*)(ws + 129280);    // 512000 B
    signed char*   imp8  = (signed char*)(ws + 641280);    // 512000 B
    int4*          aux   = (int4*)(ws + 1153280);          // 512000 B
    float*         parts = (float*)(ws + 1665280);         // 1179648 B
    unsigned char* Wpk8  = (unsigned char*)(ws + 2844928); // 6144 B
    _Float16*      Wpk16 = (_Float16*)(ws + 2851072);      // 8192 B
    float*         F1    = (float*)(ws + 2859264);         // 32768000 B (~35.6 MB total)

    build_nbrs_k<<<NN, 64, 0, stream>>>(adj, nbrs, gsum);
    build_map_prep_k<<<165, 256, 0, stream>>>(nbrs, map8, imp8, aux, W1, W2, Wpk8, Wpk16);
    // parts: slot0 = F0 [16][2048] | slot1 = F1 [16][8192] | slot2 = F2 [16][8192]
    step_k<1><<<NN, 256, 0, stream>>>(nullptr, X, Wpk8, Wpk16, b1, map8, imp8, aux, F1,
                                      parts, parts + 32768,
                                      nullptr, nullptr, nullptr, nullptr, nullptr);
    step_k<0><<<NN, 256, 0, stream>>>(F1, X, Wpk8 + 3072, Wpk16 + 2048, b2, map8, imp8, aux,
                                      nullptr, nullptr, parts + 163840,
                                      parts, gsum, fcw, fcb, out);
}

// Round 9
// 143.997 us; speedup vs baseline: 1.4245x; 1.4146x over previous
//
#include <hip/hip_runtime.h>

#define NN 2000

typedef _Float16 halfx8 __attribute__((ext_vector_type(8)));
typedef float floatx4 __attribute__((ext_vector_type(4)));

// lgkm-only barrier: LDS visibility without draining vmcnt (global loads stay
// in flight across phase boundaries). "memory" clobber pins compiler ordering.
#define LBAR() asm volatile("s_waitcnt lgkmcnt(0)\n\ts_barrier" ::: "memory")

// f32 -> OCP fp8 e4m3 (gfx950 HW convert; same format the fp8 MFMA consumes)
__device__ __forceinline__ unsigned char to_fp8(float v) {
    return (unsigned char)(__builtin_amdgcn_cvt_pk_fp8_f32(v, 0.f, 0, false) & 0xff);
}

// ---------------------------------------------------------------------------
// Kernel 1 (fused): blocks 0..NN-1 build sorted neighbor lists (float4 adj
// loads, 4-ballot prefix scan); blocks NN.. pack W1/W2 MFMA B-fragments
// (independent work — one dispatch). Also zero-inits the finalize acc+counter.
// NOTE (R6 lesson): never fuse all-producer publication into step_k — a
// per-block __threadfence on 8-XCD CDNA4 = L2 writeback per block (~55 us).
// PRE chunks (maps, fp8 e4m3): c0=(blk2|blk4) c1=(blk6|blk8) c2=(blk10|-)
//   for ACC1; c3=(3|5) c4=(7|9) c5=(11|-) for ACC2.  (k<16 -> first blk)
// POST chunks (S0/V, f16): d0=(blk0|blk12) d1=(blk14|blk16) ACC1;
//   d2=(1|13) d3=(15|17) ACC2.
// B-frag: lane L holds B[k=(L>>4)*8+j][n=L&15].
// ---------------------------------------------------------------------------
__global__ void build_nbrs_k(const float* __restrict__ adj,
                             int* __restrict__ nbrs,
                             float* __restrict__ gsum,
                             const float* __restrict__ W1,
                             const float* __restrict__ W2,
                             unsigned char* __restrict__ Wpk8,
                             _Float16* __restrict__ Wpk16) {
    int i = blockIdx.x;
    int lane = threadIdx.x;
    if (i >= NN) {
        // ---- weight-packing blocks: 160 x 64 = 10240 elements ----
        int idx = (i - NN) * 64 + lane;
        if (idx >= 10240) return;
        if (idx < 6144) {            // fp8 PRE: [2][6][64][8] bytes
            int stage = idx / 3072;
            int r = idx % 3072;
            int c = r / 512;
            int r2 = r % 512;
            int L = r2 >> 3, jj = r2 & 7;
            int q = L >> 4, h = L & 15;
            int k = q * 8 + jj;
            const int bA[6] = {2, 6, 10, 3, 7, 11};
            const int bB[6] = {4, 8, -1, 5, 9, -1};
            int tb = (k < 16) ? bA[c] : bB[c];
            int ci = k & 15;
            const float* W = stage ? W2 : W1;
            float val = (tb < 0) ? 0.f : W[h * 288 + tb * 16 + ci];
            Wpk8[idx] = to_fp8(val);
        } else {                     // f16 POST: [2][4][64][8] halves
            int id2 = idx - 6144;
            int stage = id2 / 2048;
            int r = id2 % 2048;
            int c = r / 512;
            int r2 = r % 512;
            int L = r2 >> 3, jj = r2 & 7;
            int q = L >> 4, h = L & 15;
            int k = q * 8 + jj;
            const int bA[4] = {0, 14, 1, 15};
            const int bB[4] = {12, 16, 13, 17};
            int tb = (k < 16) ? bA[c] : bB[c];
            int ci = k & 15;
            const float* W = stage ? W2 : W1;
            float val = W[h * 288 + tb * 16 + ci];
            Wpk16[id2] = (_Float16)val;
        }
        return;
    }
    if (i == 0 && lane == 0) {
        gsum[0] = 0.0f;                      // fused-finalize accumulator
        ((unsigned*)gsum)[1] = 0u;           // completion counter
    }
    const float4* row = (const float4*)(adj + (size_t)i * NN);  // 500 float4s
    float4 v[8];
#pragma unroll
    for (int c = 0; c < 8; ++c) {
        int idx4 = c * 64 + lane;
        if (idx4 < 500) v[c] = row[idx4];
        else            v[c] = make_float4(0.f, 0.f, 0.f, 0.f);
    }
    int base = 0;
#pragma unroll
    for (int c = 0; c < 8; ++c) {
        unsigned nib = (v[c].x > 0.5f ? 1u : 0u) | (v[c].y > 0.5f ? 2u : 0u) |
                       (v[c].z > 0.5f ? 4u : 0u) | (v[c].w > 0.5f ? 8u : 0u);
        unsigned long long b0 = __ballot(nib & 1u);
        unsigned long long b1 = __ballot(nib & 2u);
        unsigned long long b2 = __ballot(nib & 4u);
        unsigned long long b3 = __ballot(nib & 8u);
        unsigned long long below = (1ull << lane) - 1ull;
        int pos = base + __popcll(b0 & below) + __popcll(b1 & below) +
                         __popcll(b2 & below) + __popcll(b3 & below);
        int col0 = c * 256 + lane * 4;
        if (nib & 1u) { nbrs[i * 16 + pos] = col0;     ++pos; }
        if (nib & 2u) { nbrs[i * 16 + pos] = col0 + 1; ++pos; }
        if (nib & 4u) { nbrs[i * 16 + pos] = col0 + 2; ++pos; }
        if (nib & 8u) { nbrs[i * 16 + pos] = col0 + 3; ++pos; }
        base += __popcll(b0) + __popcll(b1) + __popcll(b2) + __popcll(b3);
    }
}

// ---------------------------------------------------------------------------
// Kernel 2: one CCN step per node. chi = partial permutation =>
// T[m,a,b,c] = Fp[j, mp(a), mp(b), c].
// NEW: neighbor maps are built IN-REGISTER from nbrs (replaces the old
// build_map_k dispatch + map8/imp8/aux traffic):
//   group g of a wave occupies ballot bits [16g,16g+16);
//   mp[a] = p : nbrs[j][p]==nbrs[i][a]   via 16x __ballot(nj_l == ni[a])
//   iv[p] = a : nbrs[i][a]==nbrs[j][p]   via 16x __shfl-broadcast + __ballot
//   (both packed 4x u32 bytes, 0xff = none — same encoding the aux/imp8
//   buffers used; all downstream decode logic unchanged -> integer-exact.)
// Overlap is never empty: j in nbrs[i] and j in nbrs[j] (self-loop) => a1>=0.
//   S0 f32 stride-16 (self plain + sparse LDS atomics), maps A2/A4/A6/A8/A10
//   in fp8 (wave-private rows), V0 plain, V1/V2 f32 atomics.
// 18-block contraction: PRE chunks on mfma_f32_16x16x32_fp8_fp8 before
// barrier B, POST chunks (S0/V) on f16 MFMA after — both chain into the same
// fp32 accumulators (C/D layout is dtype-independent on gfx950).
// LDS total = 40960 B -> 4 blocks/CU. __launch_bounds__(256,3): (256,4)
// forced VGPR=64 -> scratch spills. NO device-scope fence/atomic here (R6).
// ---------------------------------------------------------------------------
template <int DIAG>
__global__ __launch_bounds__(256, 3)
void step_k(const float* __restrict__ Fp,    // (N,16,16,16) or null (DIAG)
            const float* __restrict__ Xp,    // (N,16) when DIAG
            const unsigned char* __restrict__ Wpk8s,  // this stage's fp8 B-frags (3072 B)
            const _Float16* __restrict__ Wpk16s,      // this stage's f16 B-frags (2048 h)
            const float* __restrict__ bias,  // (16)
            const int* __restrict__ nbrs,    // (N,16) sorted neighbor lists
            float* __restrict__ Fout,        // (N,16,16,16) or null
            float* __restrict__ gp0,         // [16][2048] h-major F0 partials (DIAG)
            float* __restrict__ gp) {        // [16][8192] h-major per-wave partials
    __shared__ __attribute__((aligned(16))) float S0[16][16][16];            // 16384
    __shared__ __attribute__((aligned(16))) unsigned char MAP8[5][16][16][16];// 20480 (reused as P2 post-B)
    __shared__ __attribute__((aligned(16))) float V0f[16][16];               // 1024
    __shared__ __attribute__((aligned(16))) float V1f[16][16];               // 1024
    __shared__ __attribute__((aligned(16))) float V2f[16][16];               // 1024
    __shared__ __attribute__((aligned(16))) float S1f[16][16];               // 1024: self rowsums / Xs
    // total 40960 B -> 4 blocks/CU

    const int i = blockIdx.x;
    const int t = threadIdx.x;
    const int u = t >> 4;        // group id (= m / tile row)
    const int l = t & 15;        // lane in group (= channel)
    const int lane = t & 63, q = lane >> 4, h = lane & 15, wv = t >> 6;
    const int gsh = lane & 48;   // this group's bit offset in wave ballots

    // ---- prologue: issue independent global loads first ----
    const int* nbi = nbrs + (size_t)i * 16;
    const int j    = nbi[u];            // this group's neighbor
    const int ni_l = nbi[l];            // nbrs[i][l] (for inverse-map ballots)
    int4 n0 = ((const int4*)nbi)[0], n1 = ((const int4*)nbi)[1],
         n2 = ((const int4*)nbi)[2], n3 = ((const int4*)nbi)[3];
    float bv = bias[l];

    float frow[16], fcol[16], xv = 0.f;
    if (DIAG) {
        xv = Xp[(size_t)j * 16 + l];
    } else {
        const float* Fi = Fp + (size_t)i * 4096;
#pragma unroll
        for (int b = 0; b < 16; ++b) frow[b] = Fi[(u * 16 + b) * 16 + l];
#pragma unroll
        for (int a = 0; a < 16; ++a) fcol[a] = Fi[(a * 16 + u) * 16 + l];
    }
    // B-frags: packed weights, issued early -> stay in flight
    long Bf8[6];
    {
        const long* Wq8 = (const long*)Wpk8s;
#pragma unroll
        for (int c = 0; c < 6; ++c) Bf8[c] = Wq8[c * 64 + lane];
    }
    halfx8 Bf16[4];
    {
        const halfx8* Wq16 = (const halfx8*)Wpk16s;
#pragma unroll
        for (int c = 0; c < 4; ++c) Bf16[c] = Wq16[c * 64 + lane];
    }
    const int nj_l = nbrs[(size_t)j * 16 + l];   // chained on j

    // ---- in-register neighbor-map build ----
    int ms = 0, a1 = -1, a2 = -1, pa1 = 0, pa2 = 0;
    unsigned vm = 0, mpq0 = 0, mpq1 = 0, mpq2 = 0, mpq3 = 0;
    {
        const int niA[16] = {n0.x, n0.y, n0.z, n0.w, n1.x, n1.y, n1.z, n1.w,
                             n2.x, n2.y, n2.z, n2.w, n3.x, n3.y, n3.z, n3.w};
#pragma unroll
        for (int a = 0; a < 16; ++a)
            if (niA[a] == i) ms = a;
#pragma unroll
        for (int a = 0; a < 16; ++a) {
            unsigned long long b = __ballot(nj_l == niA[a]);
            unsigned gm = (unsigned)(b >> gsh) & 0xffffu;
            unsigned pb = 0xffu;
            if (gm) {
                int p = __builtin_ctz(gm);
                pb = (unsigned)p;
                vm |= (1u << a);
                if (a1 < 0)      { a1 = a; pa1 = p; }
                else if (a2 < 0) { a2 = a; pa2 = p; }
            }
            unsigned sh = 8u * (a & 3);
            if (a < 4)       mpq0 |= pb << sh;
            else if (a < 8)  mpq1 |= pb << sh;
            else if (a < 12) mpq2 |= pb << sh;
            else             mpq3 |= pb << sh;
        }
    }
    // pmm = mp[m=u] as unsigned byte (0xff if none — never matches p<16)
    unsigned dwu = (u < 4) ? mpq0 : ((u < 8) ? mpq1 : ((u < 12) ? mpq2 : mpq3));
    const int pmm = (int)((dwu >> (8 * (u & 3))) & 0xffu);

    // inverse map iv[p] = a : nbrs[i][a]==nbrs[j][p] (packed bytes, 0xff=none)
    unsigned iv0 = 0, iv1 = 0, iv2 = 0, iv3 = 0;
    if (!DIAG) {
#pragma unroll
        for (int p = 0; p < 16; ++p) {
            int njp = __shfl(nj_l, gsh + p, 64);     // group-local broadcast
            unsigned long long b = __ballot(ni_l == njp);
            unsigned gm = (unsigned)(b >> gsh) & 0xffffu;
            unsigned ab = gm ? (unsigned)__builtin_ctz(gm) : 0xffu;
            unsigned sh = 8u * (p & 3);
            if (p < 4)       iv0 |= ab << sh;
            else if (p < 8)  iv1 |= ab << sh;
            else if (p < 12) iv2 |= ab << sh;
            else             iv3 |= ab << sh;
        }
    }

    // gather prefetch: rows for first (and second) valid a
    float R1[16], R2[16];
    if (!DIAG && u != ms) {
        const float* P1 = Fp + (((size_t)j * 256 + pa1 * 16) * 16) + l;
#pragma unroll
        for (int p = 0; p < 16; ++p) R1[p] = P1[p * 16];
        if (a2 >= 0) {
            const float* P2 = Fp + (((size_t)j * 256 + pa2 * 16) * 16) + l;
#pragma unroll
            for (int p = 0; p < 16; ++p) R2[p] = P2[p * 16];
        }
    }

    // ---- phase 1: zero MAP rows (m != ms), self-loop stores ----
    if (u != ms) {
        uint4 z = {0u, 0u, 0u, 0u};
#pragma unroll
        for (int k = 0; k < 5; ++k)
            *(uint4*)&MAP8[k][u][l][0] = z;   // fp8 row = 16 B = one uint4
    }
    if (DIAG) {
        S1f[u][l] = xv;                 // Xs staging
        V1f[u][l] = xv;
        V2f[u][l] = xv;
#pragma unroll
        for (int b = 0; b < 16; ++b) S0[u][b][l] = (b == u) ? xv : 0.f;
        unsigned char x8 = to_fp8(xv);
        MAP8[0][ms][u][l] = x8;                     // A2[ms][b=u]
        MAP8[1][ms][u][l] = x8;                     // A4[ms][a=u]
        unsigned char dz = (u == ms) ? x8 : (unsigned char)0;
        MAP8[2][ms][u][l] = dz;                     // A6[ms][b=u]
        MAP8[3][ms][u][l] = dz;                     // A8[ms][a=u]
        MAP8[4][ms][u][l] = x8;                     // A10[ms][y=u]
    } else {
        float s2 = 0.f, a10 = 0.f, a8 = 0.f;
#pragma unroll
        for (int b = 0; b < 16; ++b) {
            float v = frow[b];
            s2 += v;
            S0[u][b][l] = v;
            if (b == u)  a10 = v;       // Fi[u][u]
            if (b == ms) a8 = v;        // Fi[u][ms]
        }
        float s1 = 0.f, a6 = 0.f;
#pragma unroll
        for (int a = 0; a < 16; ++a) {
            float v = fcol[a];
            s1 += v;
            if (a == ms) a6 = v;        // Fi[ms][u]
        }
        S1f[u][l] = s2;                 // self rowsums (V0[ms] source)
        V1f[u][l] = s2;
        V2f[u][l] = s1;
        MAP8[0][ms][u][l] = to_fp8(s1);    // A2[ms][b=u]
        MAP8[1][ms][u][l] = to_fp8(s2);    // A4[ms][a=u]
        MAP8[2][ms][u][l] = to_fp8(a6);    // A6[ms][b=u]
        MAP8[3][ms][u][l] = to_fp8(a8);    // A8[ms][a=u]
        MAP8[4][ms][u][l] = to_fp8(a10);   // A10[ms][u]
    }
    LBAR();   // A

    // ---- phase 2: sparse m (group u = m); group ms does V0[ms] ----
    if (u != ms) {
        const int m = u;
        float v0acc = 0.f;
        if (DIAG) {
#pragma unroll
            for (int a = 0; a < 16; ++a) {
                if ((vm >> a) & 1u) {
                    float v = S1f[a][l];     // X[nbrs[i,a], l]
                    v0acc += v;
                    atomicAdd(&S0[a][a][l], v);
                    atomicAdd(&V1f[a][l], v);
                    atomicAdd(&V2f[a][l], v);
                    unsigned char v8 = to_fp8(v);
                    MAP8[0][m][a][l] = v8;
                    MAP8[1][m][a][l] = v8;
                    MAP8[4][m][a][l] = v8;
                    if (a == m) { MAP8[2][m][m][l] = v8; MAP8[3][m][m][l] = v8; }
                }
            }
        } else {
            float colacc[16];
#pragma unroll
            for (int p = 0; p < 16; ++p) colacc[p] = 0.f;
            auto process = [&](int a, int pa, const float (&vr)[16]) {
                float rowacc = 0.f, a8v = 0.f, a10v = 0.f;
                const bool am = (a == m);
#pragma unroll
                for (int p = 0; p < 16; ++p) {
                    float v = vr[p];
                    if (p == pmm) a8v = v;       // Fj[pa][pmm]
                    if (p == pa)  a10v = v;      // Fj[pa][pa]
                    unsigned dw = (p < 4) ? iv0 : ((p < 8) ? iv1 : ((p < 12) ? iv2 : iv3));
                    int b = (int)(signed char)((dw >> (8 * (p & 3))) & 0xffu);
                    if (b >= 0) {
                        rowacc += v;
                        colacc[p] += v;
                        atomicAdd(&S0[a][b][l], v);
                        atomicAdd(&V2f[b][l], v);
                        if (am) MAP8[2][m][b][l] = to_fp8(v);  // A6[m][b]
                    }
                }
                v0acc += rowacc;
                atomicAdd(&V1f[a][l], rowacc);
                MAP8[1][m][a][l] = to_fp8(rowacc);   // A4
                MAP8[3][m][a][l] = to_fp8(a8v);      // A8
                MAP8[4][m][a][l] = to_fp8(a10v);     // A10
            };
            process(a1, pa1, R1);
            if (a2 >= 0) process(a2, pa2, R2);
            unsigned rm = vm & ~(1u << a1);
            if (a2 >= 0) rm &= ~(1u << a2);
            if (rm) {                    // rare tail (>2 overlaps): maps in regs
                do {
                    int a = __builtin_ctz(rm); rm &= rm - 1;
                    unsigned dw2 = (a & 8) ? ((a & 4) ? mpq3 : mpq2)
                                           : ((a & 4) ? mpq1 : mpq0);
                    int pa = (int)(signed char)((dw2 >> (8 * (a & 3))) & 0xffu);
                    float RT[16];
                    const float* P3 = Fp + (((size_t)j * 256 + pa * 16) * 16) + l;
#pragma unroll
                    for (int p = 0; p < 16; ++p) RT[p] = P3[p * 16];
                    process(a, pa, RT);
                } while (rm);
            }
#pragma unroll
            for (int p = 0; p < 16; ++p) {
                unsigned dw = (p < 4) ? iv0 : ((p < 8) ? iv1 : ((p < 12) ? iv2 : iv3));
                int b = (int)(signed char)((dw >> (8 * (p & 3))) & 0xffu);
                if (b >= 0) MAP8[0][m][b][l] = to_fp8(colacc[p]);  // A2
            }
        }
        V0f[m][l] = v0acc;
    } else {
        float v0s = 0.f;
#pragma unroll
        for (int b = 0; b < 16; ++b) v0s += S1f[b][l];
        V0f[ms][l] = v0s;
        if (DIAG) gp0[l * 2048 + i] = v0s;   // h-major F0 g-partial
    }

    // ---- PRE-MFMAs (fp8): map chunks, wave-private rows -> no barrier ----
    floatx4 acc1[4], acc2[4];
#pragma unroll
    for (int tt = 0; tt < 4; ++tt) {
        acc1[tt] = (floatx4){0.f, 0.f, 0.f, 0.f};
        acc2[tt] = (floatx4){0.f, 0.f, 0.f, 0.f};
    }
    const int wbase = wv * 4;
    {
        const int off8 = (q & 1) * 8;
        const unsigned char* mA = (q < 2) ? &MAP8[0][0][0][0] : &MAP8[1][0][0][0];
        const unsigned char* mB = (q < 2) ? &MAP8[2][0][0][0] : &MAP8[3][0][0][0];
        const unsigned char* mC = &MAP8[4][0][0][0];
#pragma unroll
        for (int tt = 0; tt < 4; ++tt) {
            const int x = wbase + tt;
            const int base = x * 256 + h * 16 + off8;
            long f0 = *(const long*)(mA + base);
            long f1 = *(const long*)(mB + base);
            long f2 = (q < 2) ? *(const long*)(mC + base) : 0L;
            acc1[tt] = __builtin_amdgcn_mfma_f32_16x16x32_fp8_fp8(f0, Bf8[0], acc1[tt], 0, 0, 0);
            acc1[tt] = __builtin_amdgcn_mfma_f32_16x16x32_fp8_fp8(f1, Bf8[1], acc1[tt], 0, 0, 0);
            acc1[tt] = __builtin_amdgcn_mfma_f32_16x16x32_fp8_fp8(f2, Bf8[2], acc1[tt], 0, 0, 0);
            acc2[tt] = __builtin_amdgcn_mfma_f32_16x16x32_fp8_fp8(f0, Bf8[3], acc2[tt], 0, 0, 0);
            acc2[tt] = __builtin_amdgcn_mfma_f32_16x16x32_fp8_fp8(f1, Bf8[4], acc2[tt], 0, 0, 0);
            acc2[tt] = __builtin_amdgcn_mfma_f32_16x16x32_fp8_fp8(f2, Bf8[5], acc2[tt], 0, 0, 0);
        }
    }
    LBAR();   // B: S0 / V1 / V2 atomics complete; MAP8 globally dead after this

    // ---- POST-MFMAs (f16): S0 + V chunks ----
    auto cvt8a = [](const float* p) -> halfx8 {  // 16B-aligned f32 -> f16x8
        float4 va = *(const float4*)p, vb = *(const float4*)(p + 4);
        halfx8 r;
        r[0] = (_Float16)va.x; r[1] = (_Float16)va.y; r[2] = (_Float16)va.z; r[3] = (_Float16)va.w;
        r[4] = (_Float16)vb.x; r[5] = (_Float16)vb.y; r[6] = (_Float16)vb.z; r[7] = (_Float16)vb.w;
        return r;
    };
#pragma unroll
    for (int tt = 0; tt < 4; ++tt) {
        const int x = wbase + tt;
        halfx8 p3, p4;
        if (q < 2) {
            p3 = cvt8a(&S0[x][h][q * 8]);                // S0 (blk0/1)
            p4 = cvt8a(&V1f[x][q * 8]);                  // V1 (blk14/15)
        } else {
            const int c0 = (q - 2) * 8;
            p3 = cvt8a(&V0f[x][c0]);                     // V0 (blk12/13)
            p4 = cvt8a(&V2f[x][c0]);                     // V2 (blk16/17)
        }
        acc1[tt] = __builtin_amdgcn_mfma_f32_16x16x32_f16(p3, Bf16[0], acc1[tt], 0, 0, 0);
        acc1[tt] = __builtin_amdgcn_mfma_f32_16x16x32_f16(p4, Bf16[1], acc1[tt], 0, 0, 0);
        acc2[tt] = __builtin_amdgcn_mfma_f32_16x16x32_f16(p3, Bf16[2], acc2[tt], 0, 0, 0);
        acc2[tt] = __builtin_amdgcn_mfma_f32_16x16x32_f16(p4, Bf16[3], acc2[tt], 0, 0, 0);
    }

    // ---- transpose ACC2 through the (dead) MAP8 region; writes need no
    //      barrier (all MAP8 reads completed before barrier B) ----
    float* P2f = (float*)&MAP8[0][0][0][0];   // [r][s][h] stride 17 (17408 B <= 20480)
#pragma unroll
    for (int tt = 0; tt < 4; ++tt) {
        const int x = wbase + tt;
#pragma unroll
        for (int r = 0; r < 4; ++r)
            P2f[(x * 16 + (q * 4 + r)) * 17 + h] = acc2[tt][r];
    }
    LBAR();   // C

    // ---- epilogue: combine, relu, store; per-wave g-partials ----
    float gpart = 0.f;
#pragma unroll
    for (int tt = 0; tt < 4; ++tt) {
        const int x = wbase + tt;
#pragma unroll
        for (int r = 0; r < 4; ++r) {
            const int y = q * 4 + r;
            float val = acc1[tt][r] + P2f[(y * 16 + x) * 17 + h] + bv;
            val = fmaxf(val, 0.f);
            gpart += val;
            if (Fout) Fout[(size_t)i * 4096 + (x * 16 + y) * 16 + h] = val;
        }
    }
    gpart += __shfl_xor(gpart, 16, 64);
    gpart += __shfl_xor(gpart, 32, 64);
    if (lane < 16) gp[h * 8192 + i * 4 + wv] = gpart;   // h-major
}

// ---------------------------------------------------------------------------
// Kernel 3 (fused reduce + finalize): reduce h-major partials, then each block
// contributes s*fcw[r] to the device-scope accumulator; the LAST block to
// arrive (completion counter, release-fenced) writes out = acc + fcb.
// Only 48 blocks carry a device-scope fence — measured harmless (R2).
// parts layout: slot0 [16][2048] | slot1 [16][8192] | slot2 [16][8192]
// ---------------------------------------------------------------------------
__global__ void reduce_fin_k(const float* __restrict__ parts,
                             float* __restrict__ gsum,
                             const float* __restrict__ fcw,
                             const float* __restrict__ fcb,
                             float* __restrict__ out) {
    int r = blockIdx.x;           // 0..47
    const float* p;
    int cnt4;
    if (r < 16)      { p = parts + r * 2048;                    cnt4 = 500;  }  // 2000 floats
    else if (r < 32) { p = parts + 32768 + (r - 16) * 8192;     cnt4 = 2000; }  // 8000 floats
    else             { p = parts + 163840 + (r - 32) * 8192;    cnt4 = 2000; }
    const float4* p4 = (const float4*)p;
    int t = threadIdx.x;
    float s = 0.f;
    for (int n = t; n < cnt4; n += 256) {
        float4 v = p4[n];
        s += v.x + v.y + v.z + v.w;
    }
#pragma unroll
    for (int off = 32; off > 0; off >>= 1) s += __shfl_xor(s, off, 64);
    __shared__ float wsum[4];
    if ((t & 63) == 0) wsum[t >> 6] = s;
    __syncthreads();
    if (t == 0) {
        float tot = wsum[0] + wsum[1] + wsum[2] + wsum[3];
        atomicAdd(&gsum[0], tot * fcw[r]);           // device-scope
        __threadfence();                             // release gsum[0] add
        unsigned old = atomicAdd((unsigned*)gsum + 1, 1u);
        if (old == 47u) {
            // all 48 contributions are in coherence order before this RMW
            float acc = atomicAdd(&gsum[0], 0.0f);   // coherent read of total
            out[0] = acc + fcb[0];
        }
    }
}

extern "C" void kernel_launch(void* const* d_in, const int* in_sizes, int n_in,
                              void* d_out, int out_size, void* d_ws, size_t ws_size,
                              hipStream_t stream) {
    const float* X   = (const float*)d_in[0];
    const float* adj = (const float*)d_in[1];
    const float* W1  = (const float*)d_in[2];
    const float* b1  = (const float*)d_in[3];
    const float* W2  = (const float*)d_in[4];
    const float* b2  = (const float*)d_in[5];
    const float* fcw = (const float*)d_in[6];
    const float* fcb = (const float*)d_in[7];
    float* out = (float*)d_out;
    char* ws = (char*)d_ws;

    // workspace layout (16B-aligned; map8/imp8/aux slots retired, offsets kept):
    float*         gsum  = (float*)(ws + 0);               // 192 B (acc + counter)
    int*           nbrs  = (int*)(ws + 1024);              // 128000 B
    float*         parts = (float*)(ws + 1665280);         // 1179648 B
    unsigned char* Wpk8  = (unsigned char*)(ws + 2844928); // 6144 B
    _Float16*      Wpk16 = (_Float16*)(ws + 2851072);      // 8192 B
    float*         F1    = (float*)(ws + 2859264);         // 32768000 B (~35.6 MB total)

    // 4 dispatches (was 5): maps are built in-register inside step_k.
    build_nbrs_k<<<NN + 160, 64, 0, stream>>>(adj, nbrs, gsum, W1, W2, Wpk8, Wpk16);
    // parts: slot0 = F0 [16][2048] | slot1 = F1 [16][8192] | slot2 = F2 [16][8192]
    step_k<1><<<NN, 256, 0, stream>>>(nullptr, X, Wpk8, Wpk16, b1, nbrs, F1,
                                      parts, parts + 32768);
    step_k<0><<<NN, 256, 0, stream>>>(F1, X, Wpk8 + 3072, Wpk16 + 2048, b2, nbrs,
                                      nullptr, nullptr, parts + 163840);
    reduce_fin_k<<<48, 256, 0, stream>>>(parts, gsum, fcw, fcb, out);
}

// Round 14
// 138.846 us; speedup vs baseline: 1.4774x; 1.0371x over previous
//
#include <hip/hip_runtime.h>

#define NN 2000

typedef _Float16 halfx8 __attribute__((ext_vector_type(8)));
typedef float floatx4 __attribute__((ext_vector_type(4)));

// lgkm-only barrier: LDS visibility without draining vmcnt (global loads stay
// in flight across phase boundaries). "memory" clobber pins compiler ordering.
#define LBAR() asm volatile("s_waitcnt lgkmcnt(0)\n\ts_barrier" ::: "memory")

// f32 -> OCP fp8 e4m3 (gfx950 HW convert; same format the fp8 MFMA consumes)
__device__ __forceinline__ unsigned char to_fp8(float v) {
    return (unsigned char)(__builtin_amdgcn_cvt_pk_fp8_f32(v, 0.f, 0, false) & 0xff);
}

// f16-PAIR LDS atomic add via 32-bit CAS (ROCm 7.2 has NO atomicAdd(__half2*)
// — R12 compile fail). Caller guarantees the guard is GROUP-uniform, so all 16
// lanes of the group arrive together: even lane l fetches lane l+1's value by
// __shfl_down and CAS-adds the aligned 4B pair word. Conflicts only occur
// cross-group on the same (a,b) word -> retries are rare.
__device__ __forceinline__ void s0_pair_add(_Float16* row, int l, float v) {
    float vh = __shfl_down(v, 1, 64);        // lane l+1 (same group; active)
    if ((l & 1) == 0) {
        unsigned* w = (unsigned*)(row + l);  // l even -> 4B aligned pair
        unsigned old = *(volatile unsigned*)w;
        while (true) {
            union { unsigned u; _Float16 h[2]; } cur, upd;
            cur.u = old;
            upd.h[0] = (_Float16)((float)cur.h[0] + v);
            upd.h[1] = (_Float16)((float)cur.h[1] + vh);
            unsigned seen = atomicCAS(w, old, upd.u);
            if (seen == old) break;
            old = seen;
        }
    }
}

// ---------------------------------------------------------------------------
// Kernel 1 (fused): blocks 0..NN-1 build sorted neighbor lists (float4 adj
// loads, 4-ballot prefix scan); blocks NN.. pack W1/W2 MFMA B-fragments
// (independent work — one dispatch). Also zero-inits the finalize acc+counter.
// NOTE (R6 lesson): never fuse all-producer publication into step_k — a
// per-block __threadfence on 8-XCD CDNA4 = L2 writeback per block (~55 us).
// PRE chunks (maps, fp8 e4m3): c0=(blk2|blk4) c1=(blk6|blk8) c2=(blk10|-)
//   for ACC1; c3=(3|5) c4=(7|9) c5=(11|-) for ACC2.  (k<16 -> first blk)
// POST chunks (S0/V, f16): d0=(blk0|blk12) d1=(blk14|blk16) ACC1;
//   d2=(1|13) d3=(15|17) ACC2.
// B-frag: lane L holds B[k=(L>>4)*8+j][n=L&15].
// ---------------------------------------------------------------------------
__global__ void build_nbrs_k(const float* __restrict__ adj,
                             int* __restrict__ nbrs,
                             float* __restrict__ gsum,
                             const float* __restrict__ W1,
                             const float* __restrict__ W2,
                             unsigned char* __restrict__ Wpk8,
                             _Float16* __restrict__ Wpk16) {
    int i = blockIdx.x;
    int lane = threadIdx.x;
    if (i >= NN) {
        // ---- weight-packing blocks: 160 x 64 = 10240 elements ----
        int idx = (i - NN) * 64 + lane;
        if (idx >= 10240) return;
        if (idx < 6144) {            // fp8 PRE: [2][6][64][8] bytes
            int stage = idx / 3072;
            int r = idx % 3072;
            int c = r / 512;
            int r2 = r % 512;
            int L = r2 >> 3, jj = r2 & 7;
            int q = L >> 4, h = L & 15;
            int k = q * 8 + jj;
            const int bA[6] = {2, 6, 10, 3, 7, 11};
            const int bB[6] = {4, 8, -1, 5, 9, -1};
            int tb = (k < 16) ? bA[c] : bB[c];
            int ci = k & 15;
            const float* W = stage ? W2 : W1;
            float val = (tb < 0) ? 0.f : W[h * 288 + tb * 16 + ci];
            Wpk8[idx] = to_fp8(val);
        } else {                     // f16 POST: [2][4][64][8] halves
            int id2 = idx - 6144;
            int stage = id2 / 2048;
            int r = id2 % 2048;
            int c = r / 512;
            int r2 = r % 512;
            int L = r2 >> 3, jj = r2 & 7;
            int q = L >> 4, h = L & 15;
            int k = q * 8 + jj;
            const int bA[4] = {0, 14, 1, 15};
            const int bB[4] = {12, 16, 13, 17};
            int tb = (k < 16) ? bA[c] : bB[c];
            int ci = k & 15;
            const float* W = stage ? W2 : W1;
            float val = W[h * 288 + tb * 16 + ci];
            Wpk16[id2] = (_Float16)val;
        }
        return;
    }
    if (i == 0 && lane == 0) {
        gsum[0] = 0.0f;                      // fused-finalize accumulator
        ((unsigned*)gsum)[1] = 0u;           // completion counter
    }
    const float4* row = (const float4*)(adj + (size_t)i * NN);  // 500 float4s
    float4 v[8];
#pragma unroll
    for (int c = 0; c < 8; ++c) {
        int idx4 = c * 64 + lane;
        if (idx4 < 500) v[c] = row[idx4];
        else            v[c] = make_float4(0.f, 0.f, 0.f, 0.f);
    }
    int base = 0;
#pragma unroll
    for (int c = 0; c < 8; ++c) {
        unsigned nib = (v[c].x > 0.5f ? 1u : 0u) | (v[c].y > 0.5f ? 2u : 0u) |
                       (v[c].z > 0.5f ? 4u : 0u) | (v[c].w > 0.5f ? 8u : 0u);
        unsigned long long b0 = __ballot(nib & 1u);
        unsigned long long b1 = __ballot(nib & 2u);
        unsigned long long b2 = __ballot(nib & 4u);
        unsigned long long b3 = __ballot(nib & 8u);
        unsigned long long below = (1ull << lane) - 1ull;
        int pos = base + __popcll(b0 & below) + __popcll(b1 & below) +
                         __popcll(b2 & below) + __popcll(b3 & below);
        int col0 = c * 256 + lane * 4;
        if (nib & 1u) { nbrs[i * 16 + pos] = col0;     ++pos; }
        if (nib & 2u) { nbrs[i * 16 + pos] = col0 + 1; ++pos; }
        if (nib & 4u) { nbrs[i * 16 + pos] = col0 + 2; ++pos; }
        if (nib & 8u) { nbrs[i * 16 + pos] = col0 + 3; ++pos; }
        base += __popcll(b0) + __popcll(b1) + __popcll(b2) + __popcll(b3);
    }
}

// ---------------------------------------------------------------------------
// Kernel 2: one CCN step per node. chi = partial permutation =>
// T[m,a,b,c] = Fp[j, mp(a), mp(b), c].
// Neighbor maps built IN-REGISTER from nbrs (R9, measured 144.0 us):
//   mp[a] via 16x __ballot(nj_l == ni[a]); iv[p] via __shfl + __ballot;
//   packed 4x u32 bytes, 0xff = none. Integer-exact vs old aux/imp8.
// S0 stored/accumulated in f16 (was f32) -> LDS 40960 -> 32768 B =
// EXACTLY 5 blocks/CU (was 4). step_k is latency-bound (MfmaUtil 2%,
// VALUBusy 10%, HBM 4% — R6 counters): +25% resident waves. Sparse S0 adds
// use s0_pair_add (32-bit CAS on the f16 pair; ROCm 7.2 lacks
// atomicAdd(__half2*)). POST-MFMA reads S0 f16 directly (no cvt pass).
// Precision: S0 sums have <=~4 terms; f16 accum error ~1e-3, far below the
// fp8 e4m3 maps already in the pipeline.
// 18-block contraction: PRE chunks on mfma_f32_16x16x32_fp8_fp8 before
// barrier B, POST chunks (S0/V) on f16 MFMA after — both chain into the same
// fp32 accumulators (C/D layout is dtype-independent on gfx950).
// NO device-scope fence/atomic here (R6 lesson).
// ---------------------------------------------------------------------------
template <int DIAG>
__global__ __launch_bounds__(256, 3)
void step_k(const float* __restrict__ Fp,    // (N,16,16,16) or null (DIAG)
            const float* __restrict__ Xp,    // (N,16) when DIAG
            const unsigned char* __restrict__ Wpk8s,  // this stage's fp8 B-frags (3072 B)
            const _Float16* __restrict__ Wpk16s,      // this stage's f16 B-frags (2048 h)
            const float* __restrict__ bias,  // (16)
            const int* __restrict__ nbrs,    // (N,16) sorted neighbor lists
            float* __restrict__ Fout,        // (N,16,16,16) or null
            float* __restrict__ gp0,         // [16][2048] h-major F0 partials (DIAG)
            float* __restrict__ gp) {        // [16][8192] h-major per-wave partials
    __shared__ __attribute__((aligned(16))) _Float16 S0h[16][16][16];        // 8192 (f16!)
    __shared__ __attribute__((aligned(16))) unsigned char MAP8[5][16][16][16];// 20480 (reused as P2 post-B)
    __shared__ __attribute__((aligned(16))) float V0f[16][16];               // 1024
    __shared__ __attribute__((aligned(16))) float V1f[16][16];               // 1024
    __shared__ __attribute__((aligned(16))) float V2f[16][16];               // 1024
    __shared__ __attribute__((aligned(16))) float S1f[16][16];               // 1024: self rowsums / Xs
    // total 32768 B -> 5 blocks/CU (163840/32768 exact)

    const int i = blockIdx.x;
    const int t = threadIdx.x;
    const int u = t >> 4;        // group id (= m / tile row)
    const int l = t & 15;        // lane in group (= channel)
    const int lane = t & 63, q = lane >> 4, h = lane & 15, wv = t >> 6;
    const int gsh = lane & 48;   // this group's bit offset in wave ballots

    // ---- prologue: issue independent global loads first ----
    const int* nbi = nbrs + (size_t)i * 16;
    const int j    = nbi[u];            // this group's neighbor
    const int ni_l = nbi[l];            // nbrs[i][l] (for inverse-map ballots)
    int4 n0 = ((const int4*)nbi)[0], n1 = ((const int4*)nbi)[1],
         n2 = ((const int4*)nbi)[2], n3 = ((const int4*)nbi)[3];
    float bv = bias[l];

    float frow[16], fcol[16], xv = 0.f;
    if (DIAG) {
        xv = Xp[(size_t)j * 16 + l];
    } else {
        const float* Fi = Fp + (size_t)i * 4096;
#pragma unroll
        for (int b = 0; b < 16; ++b) frow[b] = Fi[(u * 16 + b) * 16 + l];
#pragma unroll
        for (int a = 0; a < 16; ++a) fcol[a] = Fi[(a * 16 + u) * 16 + l];
    }
    // B-frags: packed weights, issued early -> stay in flight
    long Bf8[6];
    {
        const long* Wq8 = (const long*)Wpk8s;
#pragma unroll
        for (int c = 0; c < 6; ++c) Bf8[c] = Wq8[c * 64 + lane];
    }
    halfx8 Bf16[4];
    {
        const halfx8* Wq16 = (const halfx8*)Wpk16s;
#pragma unroll
        for (int c = 0; c < 4; ++c) Bf16[c] = Wq16[c * 64 + lane];
    }
    const int nj_l = nbrs[(size_t)j * 16 + l];   // chained on j

    // ---- in-register neighbor-map build ----
    int ms = 0, a1 = -1, a2 = -1, pa1 = 0, pa2 = 0;
    unsigned vm = 0, mpq0 = 0, mpq1 = 0, mpq2 = 0, mpq3 = 0;
    {
        const int niA[16] = {n0.x, n0.y, n0.z, n0.w, n1.x, n1.y, n1.z, n1.w,
                             n2.x, n2.y, n2.z, n2.w, n3.x, n3.y, n3.z, n3.w};
#pragma unroll
        for (int a = 0; a < 16; ++a)
            if (niA[a] == i) ms = a;
#pragma unroll
        for (int a = 0; a < 16; ++a) {
            unsigned long long b = __ballot(nj_l == niA[a]);
            unsigned gm = (unsigned)(b >> gsh) & 0xffffu;
            unsigned pb = 0xffu;
            if (gm) {
                int p = __builtin_ctz(gm);
                pb = (unsigned)p;
                vm |= (1u << a);
                if (a1 < 0)      { a1 = a; pa1 = p; }
                else if (a2 < 0) { a2 = a; pa2 = p; }
            }
            unsigned sh = 8u * (a & 3);
            if (a < 4)       mpq0 |= pb << sh;
            else if (a < 8)  mpq1 |= pb << sh;
            else if (a < 12) mpq2 |= pb << sh;
            else             mpq3 |= pb << sh;
        }
    }
    // pmm = mp[m=u] as unsigned byte (0xff if none — never matches p<16)
    unsigned dwu = (u < 4) ? mpq0 : ((u < 8) ? mpq1 : ((u < 12) ? mpq2 : mpq3));
    const int pmm = (int)((dwu >> (8 * (u & 3))) & 0xffu);

    // inverse map iv[p] = a : nbrs[i][a]==nbrs[j][p] (packed bytes, 0xff=none)
    unsigned iv0 = 0, iv1 = 0, iv2 = 0, iv3 = 0;
    if (!DIAG) {
#pragma unroll
        for (int p = 0; p < 16; ++p) {
            int njp = __shfl(nj_l, gsh + p, 64);     // group-local broadcast
            unsigned long long b = __ballot(ni_l == njp);
            unsigned gm = (unsigned)(b >> gsh) & 0xffffu;
            unsigned ab = gm ? (unsigned)__builtin_ctz(gm) : 0xffu;
            unsigned sh = 8u * (p & 3);
            if (p < 4)       iv0 |= ab << sh;
            else if (p < 8)  iv1 |= ab << sh;
            else if (p < 12) iv2 |= ab << sh;
            else             iv3 |= ab << sh;
        }
    }

    // gather prefetch: rows for first (and second) valid a
    float R1[16], R2[16];
    if (!DIAG && u != ms) {
        const float* P1 = Fp + (((size_t)j * 256 + pa1 * 16) * 16) + l;
#pragma unroll
        for (int p = 0; p < 16; ++p) R1[p] = P1[p * 16];
        if (a2 >= 0) {
            const float* P2 = Fp + (((size_t)j * 256 + pa2 * 16) * 16) + l;
#pragma unroll
            for (int p = 0; p < 16; ++p) R2[p] = P2[p * 16];
        }
    }

    // ---- phase 1: zero MAP rows (m != ms), self-loop stores ----
    if (u != ms) {
        uint4 z = {0u, 0u, 0u, 0u};
#pragma unroll
        for (int k = 0; k < 5; ++k)
            *(uint4*)&MAP8[k][u][l][0] = z;   // fp8 row = 16 B = one uint4
    }
    if (DIAG) {
        S1f[u][l] = xv;                 // Xs staging
        V1f[u][l] = xv;
        V2f[u][l] = xv;
#pragma unroll
        for (int b = 0; b < 16; ++b) S0h[u][b][l] = (_Float16)((b == u) ? xv : 0.f);
        unsigned char x8 = to_fp8(xv);
        MAP8[0][ms][u][l] = x8;                     // A2[ms][b=u]
        MAP8[1][ms][u][l] = x8;                     // A4[ms][a=u]
        unsigned char dz = (u == ms) ? x8 : (unsigned char)0;
        MAP8[2][ms][u][l] = dz;                     // A6[ms][b=u]
        MAP8[3][ms][u][l] = dz;                     // A8[ms][a=u]
        MAP8[4][ms][u][l] = x8;                     // A10[ms][y=u]
    } else {
        float s2 = 0.f, a10 = 0.f, a8 = 0.f;
#pragma unroll
        for (int b = 0; b < 16; ++b) {
            float v = frow[b];
            s2 += v;
            S0h[u][b][l] = (_Float16)v;
            if (b == u)  a10 = v;       // Fi[u][u]
            if (b == ms) a8 = v;        // Fi[u][ms]
        }
        float s1 = 0.f, a6 = 0.f;
#pragma unroll
        for (int a = 0; a < 16; ++a) {
            float v = fcol[a];
            s1 += v;
            if (a == ms) a6 = v;        // Fi[ms][u]
        }
        S1f[u][l] = s2;                 // self rowsums (V0[ms] source)
        V1f[u][l] = s2;
        V2f[u][l] = s1;
        MAP8[0][ms][u][l] = to_fp8(s1);    // A2[ms][b=u]
        MAP8[1][ms][u][l] = to_fp8(s2);    // A4[ms][a=u]
        MAP8[2][ms][u][l] = to_fp8(a6);    // A6[ms][b=u]
        MAP8[3][ms][u][l] = to_fp8(a8);    // A8[ms][a=u]
        MAP8[4][ms][u][l] = to_fp8(a10);   // A10[ms][u]
    }
    LBAR();   // A

    // ---- phase 2: sparse m (group u = m); group ms does V0[ms] ----
    if (u != ms) {
        const int m = u;
        float v0acc = 0.f;
        if (DIAG) {
#pragma unroll
            for (int a = 0; a < 16; ++a) {
                if ((vm >> a) & 1u) {           // group-uniform guard
                    float v = S1f[a][l];        // X[nbrs[i,a], l]
                    v0acc += v;
                    s0_pair_add(&S0h[a][a][0], l, v);
                    atomicAdd(&V1f[a][l], v);
                    atomicAdd(&V2f[a][l], v);
                    unsigned char v8 = to_fp8(v);
                    MAP8[0][m][a][l] = v8;
                    MAP8[1][m][a][l] = v8;
                    MAP8[4][m][a][l] = v8;
                    if (a == m) { MAP8[2][m][m][l] = v8; MAP8[3][m][m][l] = v8; }
                }
            }
        } else {
            float colacc[16];
#pragma unroll
            for (int p = 0; p < 16; ++p) colacc[p] = 0.f;
            auto process = [&](int a, int pa, const float (&vr)[16]) {
                float rowacc = 0.f, a8v = 0.f, a10v = 0.f;
                const bool am = (a == m);
#pragma unroll
                for (int p = 0; p < 16; ++p) {
                    float v = vr[p];
                    if (p == pmm) a8v = v;       // Fj[pa][pmm]
                    if (p == pa)  a10v = v;      // Fj[pa][pa]
                    unsigned dw = (p < 4) ? iv0 : ((p < 8) ? iv1 : ((p < 12) ? iv2 : iv3));
                    int b = (int)(signed char)((dw >> (8 * (p & 3))) & 0xffu);
                    if (b >= 0) {               // group-uniform guard
                        rowacc += v;
                        colacc[p] += v;
                        s0_pair_add(&S0h[a][b][0], l, v);
                        atomicAdd(&V2f[b][l], v);
                        if (am) MAP8[2][m][b][l] = to_fp8(v);  // A6[m][b]
                    }
                }
                v0acc += rowacc;
                atomicAdd(&V1f[a][l], rowacc);
                MAP8[1][m][a][l] = to_fp8(rowacc);   // A4
                MAP8[3][m][a][l] = to_fp8(a8v);      // A8
                MAP8[4][m][a][l] = to_fp8(a10v);     // A10
            };
            process(a1, pa1, R1);
            if (a2 >= 0) process(a2, pa2, R2);
            unsigned rm = vm & ~(1u << a1);
            if (a2 >= 0) rm &= ~(1u << a2);
            if (rm) {                    // rare tail (>2 overlaps): maps in regs
                do {
                    int a = __builtin_ctz(rm); rm &= rm - 1;
                    unsigned dw2 = (a & 8) ? ((a & 4) ? mpq3 : mpq2)
                                           : ((a & 4) ? mpq1 : mpq0);
                    int pa = (int)(signed char)((dw2 >> (8 * (a & 3))) & 0xffu);
                    float RT[16];
                    const float* P3 = Fp + (((size_t)j * 256 + pa * 16) * 16) + l;
#pragma unroll
                    for (int p = 0; p < 16; ++p) RT[p] = P3[p * 16];
                    process(a, pa, RT);
                } while (rm);
            }
#pragma unroll
            for (int p = 0; p < 16; ++p) {
                unsigned dw = (p < 4) ? iv0 : ((p < 8) ? iv1 : ((p < 12) ? iv2 : iv3));
                int b = (int)(signed char)((dw >> (8 * (p & 3))) & 0xffu);
                if (b >= 0) MAP8[0][m][b][l] = to_fp8(colacc[p]);  // A2
            }
        }
        V0f[m][l] = v0acc;
    } else {
        float v0s = 0.f;
#pragma unroll
        for (int b = 0; b < 16; ++b) v0s += S1f[b][l];
        V0f[ms][l] = v0s;
        if (DIAG) gp0[l * 2048 + i] = v0s;   // h-major F0 g-partial
    }

    // ---- PRE-MFMAs (fp8): map chunks, wave-private rows -> no barrier ----
    floatx4 acc1[4], acc2[4];
#pragma unroll
    for (int tt = 0; tt < 4; ++tt) {
        acc1[tt] = (floatx4){0.f, 0.f, 0.f, 0.f};
        acc2[tt] = (floatx4){0.f, 0.f, 0.f, 0.f};
    }
    const int wbase = wv * 4;
    {
        const int off8 = (q & 1) * 8;
        const unsigned char* mA = (q < 2) ? &MAP8[0][0][0][0] : &MAP8[1][0][0][0];
        const unsigned char* mB = (q < 2) ? &MAP8[2][0][0][0] : &MAP8[3][0][0][0];
        const unsigned char* mC = &MAP8[4][0][0][0];
#pragma unroll
        for (int tt = 0; tt < 4; ++tt) {
            const int x = wbase + tt;
            const int base = x * 256 + h * 16 + off8;
            long f0 = *(const long*)(mA + base);
            long f1 = *(const long*)(mB + base);
            long f2 = (q < 2) ? *(const long*)(mC + base) : 0L;
            acc1[tt] = __builtin_amdgcn_mfma_f32_16x16x32_fp8_fp8(f0, Bf8[0], acc1[tt], 0, 0, 0);
            acc1[tt] = __builtin_amdgcn_mfma_f32_16x16x32_fp8_fp8(f1, Bf8[1], acc1[tt], 0, 0, 0);
            acc1[tt] = __builtin_amdgcn_mfma_f32_16x16x32_fp8_fp8(f2, Bf8[2], acc1[tt], 0, 0, 0);
            acc2[tt] = __builtin_amdgcn_mfma_f32_16x16x32_fp8_fp8(f0, Bf8[3], acc2[tt], 0, 0, 0);
            acc2[tt] = __builtin_amdgcn_mfma_f32_16x16x32_fp8_fp8(f1, Bf8[4], acc2[tt], 0, 0, 0);
            acc2[tt] = __builtin_amdgcn_mfma_f32_16x16x32_fp8_fp8(f2, Bf8[5], acc2[tt], 0, 0, 0);
        }
    }
    LBAR();   // B: S0 / V1 / V2 atomics complete; MAP8 globally dead after this

    // ---- POST-MFMAs (f16): S0 + V chunks ----
    auto cvt8a = [](const float* p) -> halfx8 {  // 16B-aligned f32 -> f16x8
        float4 va = *(const float4*)p, vb = *(const float4*)(p + 4);
        halfx8 r;
        r[0] = (_Float16)va.x; r[1] = (_Float16)va.y; r[2] = (_Float16)va.z; r[3] = (_Float16)va.w;
        r[4] = (_Float16)vb.x; r[5] = (_Float16)vb.y; r[6] = (_Float16)vb.z; r[7] = (_Float16)vb.w;
        return r;
    };
#pragma unroll
    for (int tt = 0; tt < 4; ++tt) {
        const int x = wbase + tt;
        halfx8 p3, p4;
        if (q < 2) {
            p3 = *(const halfx8*)&S0h[x][h][q * 8];      // S0 f16 direct (blk0/1)
            p4 = cvt8a(&V1f[x][q * 8]);                  // V1 (blk14/15)
        } else {
            const int c0 = (q - 2) * 8;
            p3 = cvt8a(&V0f[x][c0]);                     // V0 (blk12/13)
            p4 = cvt8a(&V2f[x][c0]);                     // V2 (blk16/17)
        }
        acc1[tt] = __builtin_amdgcn_mfma_f32_16x16x32_f16(p3, Bf16[0], acc1[tt], 0, 0, 0);
        acc1[tt] = __builtin_amdgcn_mfma_f32_16x16x32_f16(p4, Bf16[1], acc1[tt], 0, 0, 0);
        acc2[tt] = __builtin_amdgcn_mfma_f32_16x16x32_f16(p3, Bf16[2], acc2[tt], 0, 0, 0);
        acc2[tt] = __builtin_amdgcn_mfma_f32_16x16x32_f16(p4, Bf16[3], acc2[tt], 0, 0, 0);
    }

    // ---- transpose ACC2 through the (dead) MAP8 region; writes need no
    //      barrier (all MAP8 reads completed before barrier B) ----
    float* P2f = (float*)&MAP8[0][0][0][0];   // [r][s][h] stride 17 (17408 B <= 20480)
#pragma unroll
    for (int tt = 0; tt < 4; ++tt) {
        const int x = wbase + tt;
#pragma unroll
        for (int r = 0; r < 4; ++r)
            P2f[(x * 16 + (q * 4 + r)) * 17 + h] = acc2[tt][r];
    }
    LBAR();   // C

    // ---- epilogue: combine, relu, store; per-wave g-partials ----
    float gpart = 0.f;
#pragma unroll
    for (int tt = 0; tt < 4; ++tt) {
        const int x = wbase + tt;
#pragma unroll
        for (int r = 0; r < 4; ++r) {
            const int y = q * 4 + r;
            float val = acc1[tt][r] + P2f[(y * 16 + x) * 17 + h] + bv;
            val = fmaxf(val, 0.f);
            gpart += val;
            if (Fout) Fout[(size_t)i * 4096 + (x * 16 + y) * 16 + h] = val;
        }
    }
    gpart += __shfl_xor(gpart, 16, 64);
    gpart += __shfl_xor(gpart, 32, 64);
    if (lane < 16) gp[h * 8192 + i * 4 + wv] = gpart;   // h-major
}

// ---------------------------------------------------------------------------
// Kernel 3 (fused reduce + finalize): reduce h-major partials, then each block
// contributes s*fcw[r] to the device-scope accumulator; the LAST block to
// arrive (completion counter, release-fenced) writes out = acc + fcb.
// Only 48 blocks carry a device-scope fence — measured harmless (R2).
// parts layout: slot0 [16][2048] | slot1 [16][8192] | slot2 [16][8192]
// ---------------------------------------------------------------------------
__global__ void reduce_fin_k(const float* __restrict__ parts,
                             float* __restrict__ gsum,
                             const float* __restrict__ fcw,
                             const float* __restrict__ fcb,
                             float* __restrict__ out) {
    int r = blockIdx.x;           // 0..47
    const float* p;
    int cnt4;
    if (r < 16)      { p = parts + r * 2048;                    cnt4 = 500;  }  // 2000 floats
    else if (r < 32) { p = parts + 32768 + (r - 16) * 8192;     cnt4 = 2000; }  // 8000 floats
    else             { p = parts + 163840 + (r - 32) * 8192;    cnt4 = 2000; }
    const float4* p4 = (const float4*)p;
    int t = threadIdx.x;
    float s = 0.f;
    for (int n = t; n < cnt4; n += 256) {
        float4 v = p4[n];
        s += v.x + v.y + v.z + v.w;
    }
#pragma unroll
    for (int off = 32; off > 0; off >>= 1) s += __shfl_xor(s, off, 64);
    __shared__ float wsum[4];
    if ((t & 63) == 0) wsum[t >> 6] = s;
    __syncthreads();
    if (t == 0) {
        float tot = wsum[0] + wsum[1] + wsum[2] + wsum[3];
        atomicAdd(&gsum[0], tot * fcw[r]);           // device-scope
        __threadfence();                             // release gsum[0] add
        unsigned old = atomicAdd((unsigned*)gsum + 1, 1u);
        if (old == 47u) {
            // all 48 contributions are in coherence order before this RMW
            float acc = atomicAdd(&gsum[0], 0.0f);   // coherent read of total
            out[0] = acc + fcb[0];
        }
    }
}

extern "C" void kernel_launch(void* const* d_in, const int* in_sizes, int n_in,
                              void* d_out, int out_size, void* d_ws, size_t ws_size,
                              hipStream_t stream) {
    const float* X   = (const float*)d_in[0];
    const float* adj = (const float*)d_in[1];
    const float* W1  = (const float*)d_in[2];
    const float* b1  = (const float*)d_in[3];
    const float* W2  = (const float*)d_in[4];
    const float* b2  = (const float*)d_in[5];
    const float* fcw = (const float*)d_in[6];
    const float* fcb = (const float*)d_in[7];
    float* out = (float*)d_out;
    char* ws = (char*)d_ws;

    // workspace layout (16B-aligned; map8/imp8/aux slots retired, offsets kept):
    float*         gsum  = (float*)(ws + 0);               // 192 B (acc + counter)
    int*           nbrs  = (int*)(ws + 1024);              // 128000 B
    float*         parts = (float*)(ws + 1665280);         // 1179648 B
    unsigned char* Wpk8  = (unsigned char*)(ws + 2844928); // 6144 B
    _Float16*      Wpk16 = (_Float16*)(ws + 2851072);      // 8192 B
    float*         F1    = (float*)(ws + 2859264);         // 32768000 B (~35.6 MB total)

    // 4 dispatches: maps are built in-register inside step_k.
    build_nbrs_k<<<NN + 160, 64, 0, stream>>>(adj, nbrs, gsum, W1, W2, Wpk8, Wpk16);
    // parts: slot0 = F0 [16][2048] | slot1 = F1 [16][8192] | slot2 = F2 [16][8192]
    step_k<1><<<NN, 256, 0, stream>>>(nullptr, X, Wpk8, Wpk16, b1, nbrs, F1,
                                      parts, parts + 32768);
    step_k<0><<<NN, 256, 0, stream>>>(F1, X, Wpk8 + 3072, Wpk16 + 2048, b2, nbrs,
                                      nullptr, nullptr, parts + 163840);
    reduce_fin_k<<<48, 256, 0, stream>>>(parts, gsum, fcw, fcb, out);
}